// Round 7
// baseline (347.553 us; speedup 1.0000x reference)
//
// R7: (1) #pragma unroll on ab_comp/k_nodeab load-dependent loops (latency fix
// for the 1.1-wave/SIMD small kernels); (2) wave-uniform acc1 skip for l0-tile7
// in k_pair (sender range fully beyond kl). Base: R6 (342.6 us, k_pair 78.8).
#include <hip/hip_runtime.h>
#include <hip/hip_bf16.h>

typedef unsigned long long u64;
typedef unsigned int u32;
typedef unsigned short u16;

#define NN   512
#define DIMF 64
#define E2   260
#define KPAD 272
#define MD   17
#define MH   68
#define NH1  128
#define K0   460
#define K1   358
#define K2   307
#define KT   1125
#define O1   460
#define O2   818
#define PADU 1152
#define AS   272
// 64-sender tiles per receiver, one wave each (2 MFMA acc sets of 32)
#define NT0  8
#define NT1  6
#define NT2  5
#define T0T   (K0*NT0)          // 3680
#define T01T  (T0T + K1*NT1)    // 5828
#define TTOT  (T01T + K2*NT2)   // 7363
#define PBLK  ((TTOT+3)/4)      // 1841
#define MSTR  40                // u16 stride of m-repack rows (80 B: conflict-free, R6-proven)
#define WVLDS 5120              // per-wave LDS scratch bytes (A stage 2176 < m-repack 5120)

// prescale constants: sigma(z) = rcp(1 + exp2(q)), q = -log2(e)*z; ln2*log2e == 1
#define KNEG  (-1.4426950408889634f)
#define LN2N  (-0.6931471805599453f)

typedef __attribute__((ext_vector_type(8)))  short short8;
typedef __attribute__((ext_vector_type(16))) float f32x16;

union SF  { int4 i4; u16 us[8]; u32 w[4]; short8 v; };
union F4U { float4 v; float2 h[2]; float f[4]; u32 w[4]; };

__device__ __forceinline__ float fast_exp2(float x){
#if __has_builtin(__builtin_amdgcn_exp2f)
    return __builtin_amdgcn_exp2f(x);
#else
    return __expf(x * 0.6931471805599453f);
#endif
}
__device__ __forceinline__ float fast_rcp(float x){
#if __has_builtin(__builtin_amdgcn_rcpf)
    return __builtin_amdgcn_rcpf(x);
#else
    return __fdividef(1.0f, x);
#endif
}
// prescaled silu: input q = -log2e * z, returns -log2e * silu(z)
__device__ __forceinline__ float silups(float q){
    return q * fast_rcp(1.0f + fast_exp2(q));
}
__device__ __forceinline__ float sigf(float x){
    return fast_rcp(1.0f + fast_exp2(x * KNEG));
}
__device__ __forceinline__ u16 bf16_rne(float f){
    u32 u = __float_as_uint(f);
    u += 0x7FFFu + ((u >> 16) & 1u);
    return (u16)(u >> 16);
}
__device__ __forceinline__ float bf16f(u16 h){
    return __uint_as_float(((u32)h) << 16);
}
// packed RNE bf16x2 (v_cvt_pk_bf16_f32 on gfx950)
__device__ __forceinline__ u32 pk_bf16(float x, float y){
    float2 f2; f2.x = x; f2.y = y;
    __hip_bfloat162 h = __float22bfloat162_rn(f2);
    union { __hip_bfloat162 b; u32 u; } cv; cv.b = h;
    return cv.u;
}
__device__ __forceinline__ void lgkm_wait(){
#if __has_builtin(__builtin_amdgcn_s_waitcnt)
    __builtin_amdgcn_s_waitcnt(0xC07F);   // lgkmcnt(0)
#endif
}
// packed float2 helpers (SLP-friendly -> v_pk_fma_f32 / v_pk_add_f32 / v_pk_mul_f32)
__device__ __forceinline__ float2 f2add(float2 a, float2 b){ return float2{a.x+b.x, a.y+b.y}; }
__device__ __forceinline__ float2 f2mul(float2 a, float2 b){ return float2{a.x*b.x, a.y*b.y}; }
__device__ __forceinline__ float2 f2fma(float2 a, float2 b, float2 c){
    return float2{fmaf(a.x,b.x,c.x), fmaf(a.y,b.y,c.y)};
}
// prescaled paired silu, rcp form. R3 post-mortem: this (4 trans + 2 pk) BEATS
// the deg-4 poly form (2 trans + 8 pk) on gfx950 — trans ops issue cheaply;
// total VALU slots dominate. Do NOT re-introduce sig2p.
__device__ __forceinline__ float2 sig2s(float2 q){
    float ex = fast_exp2(q.x), ey = fast_exp2(q.y);
    float2 den = f2add(float2{1.0f, 1.0f}, float2{ex, ey});
    float rx = fast_rcp(den.x), ry = fast_rcp(den.y);
    return f2mul(q, float2{rx, ry});
}

// ============ fused prep: ug bitmasks + pooling scores + weight fragments ===
__global__ __launch_bounds__(256) void k_pre(
    const float* __restrict__ edge, const float* __restrict__ feat,
    const float* __restrict__ wp, const float* __restrict__ bp,
    const float* __restrict__ We2, const float* __restrict__ Wc1,
    const float* __restrict__ We1, const float* __restrict__ be2,
    const float* __restrict__ bc1, const float* __restrict__ Wc2,
    u64* __restrict__ ugw, float* __restrict__ scores,
    u16* __restrict__ W2f, u16* __restrict__ Wc1f,
    float* __restrict__ wdP, float* __restrict__ weP, float* __restrict__ be2P,
    float* __restrict__ bc1P, float* __restrict__ Wc2P, u64* __restrict__ ug2w,
    float* __restrict__ outz){
    int blk = blockIdx.x, t = threadIdx.x;
    if (blk < 128){                      // ug row bitmasks, 4 rows/block
        int i = blk*4 + (t>>6); int lane = t&63;
        const float* row = edge + (size_t)i*NN;
        for (int w = 0; w < 8; w++){
            u64 m = __ballot(row[w*64+lane] != 0.0f);
            if (lane == 0) ugw[i*8+w] = m;
        }
        return;
    }
    if (blk < 134){                      // pooling scores (float4 dot)
        int gid = (blk-128)*256 + t; if (gid >= 3*NN) return;
        int l = gid>>9, n = gid&511;
        const float4* fr = (const float4*)(feat + n*DIMF);
        const float4* wr = (const float4*)(wp + l*DIMF);
        float s = bp[l];
        for (int d = 0; d < 16; d++){
            float4 f = fr[d], w = wr[d];
            s = fmaf(f.x, w.x, s); s = fmaf(f.y, w.y, s);
            s = fmaf(f.z, w.z, s); s = fmaf(f.w, w.w, s);
        }
        scores[gid] = sigf(s);
        return;
    }
    int idx = (blk-134)*256 + t;
    if (idx < 26112){                    // We2 frags hi-only: [jl][c17][lane64][8]
        // k==260 pad slot carries the prescaled be2 bias column (s'[260]==1).
        int e = idx&7, lane = (idx>>3)&63, c = (idx>>9)%17, jl = idx/8704;
        int q = lane>>5, nn = lane&31;
        int k = c*16 + q*8 + e;
        float v = (k < E2 && nn < MD) ? We2[jl*E2*MD + k*MD + nn]
                : (k == 260 && nn < MD) ? be2[jl*MD+nn]*KNEG : 0.0f;
        W2f[idx] = bf16_rne(v);
        return;
    }
    idx -= 26112;
    if (idx < 9216){                     // Wc1 frags: [jl][T3][c2][lane][8]
        int e = idx & 7, lane = (idx>>3)&63, c2 = (idx>>9)&1, T = (idx>>10)%3, jl = idx/3072;
        int q = lane>>5, nn = lane&31;
        int o = c2*16 + q*8 + e, h = T*32 + nn;
        float v = (o < MD && h < MH) ? Wc1[jl*MD*MH + o*MH + h] : 0.0f;
        Wc1f[idx] = bf16_rne(v);
        return;
    }
    idx -= 9216;
    if (idx < 816){ int jl = idx/KPAD, k = idx%KPAD;
        wdP[idx] = (k < E2) ? We1[jl*130*E2 + 128*E2 + k]*KNEG : 0.0f; return; }
    idx -= 816;
    if (idx < 816){ int jl = idx/KPAD, k = idx%KPAD;
        weP[idx] = (k < E2) ? We1[jl*130*E2 + 129*E2 + k]*KNEG : 0.0f; return; }
    idx -= 816;
    if (idx < 96){ int jl = idx/32, o = idx%32;
        be2P[idx] = (o < MD) ? be2[jl*MD+o]*KNEG : 0.0f; return; }
    idx -= 96;
    if (idx < 288){ int jl = idx/96, h = idx%96;
        bc1P[idx] = (h < MH) ? bc1[jl*MH+h]*KNEG : 0.0f; return; }
    idx -= 288;
    if (idx < 288){ int jl = idx/96, h = idx%96;
        Wc2P[idx] = (h < MH) ? Wc2[jl*MH+h]*LN2N : 0.0f; return; }
    idx -= 288;
    if (idx < 4096){ ug2w[idx] = 0ULL; return; }   // zero for k_sortug2's atomicOr
    idx -= 4096;
    if (idx < NN*DIMF){ outz[idx] = 0.0f; return; } // zero out for fused atomicMax scatter
}

// ============ fused: bitonic sort (3 blocks) + ug2 bitset matmul (64 blocks) =
// sort: shfl-register bitonic for jj<=32 (39 of 45 rounds barrier-free)
__global__ __launch_bounds__(512) void k_sortug2(
    const float* __restrict__ scores, const u64* __restrict__ ugw,
    float* __restrict__ svals, int* __restrict__ sidx, int* __restrict__ rev,
    u64* __restrict__ ug2w){
    int blk = blockIdx.x, t = threadIdx.x;
    if (blk < 3){
        int l = blk;
        __shared__ float sk[NN];
        __shared__ int   si[NN];
        float key = scores[l*NN+t]; int idx = t;
        rev[l*NN+t] = -1;
        for (int k = 2; k <= NN; k <<= 1){
            for (int jj = k>>1; jj > 0; jj >>= 1){
                float kb; int ib;
                if (jj >= 64){
                    sk[t] = key; si[t] = idx;
                    __syncthreads();
                    kb = sk[t^jj]; ib = si[t^jj];
                    __syncthreads();
                } else {
                    kb = __shfl_xor(key, jj);
                    ib = __shfl_xor(idx, jj);
                }
                bool aFirst = (key > kb) || (key == kb && idx < ib);
                bool down   = ((t & k) == 0);
                bool lower  = ((t & jj) == 0);
                bool keep   = (aFirst == (lower == down));
                key = keep ? key : kb;
                idx = keep ? idx : ib;
            }
        }
        svals[l*NN+t] = key; sidx[l*NN+t] = idx;
        int kcnt = (l==0)?K0:(l==1)?K1:K2;
        if (t < kcnt) rev[l*NN + idx] = t;
    } else {
        // (i, w, kc): row i, out-word w, row-mask word kc. Iterate SET BITS only.
        int gid = (blk-3)*512 + t;       // 32768 total
        int i  = gid >> 6;
        int w  = (gid >> 3) & 7;
        int kc = gid & 7;
        u64 rm = ugw[i*8 + kc];
        u64 acc = 0;
        int base = kc*64;
        while (rm){
            int k2 = __builtin_ctzll(rm);
            rm &= rm - 1;
            acc |= ugw[(base + k2)*8 + w];
        }
        if (acc) atomicOr(&ug2w[i*8 + w], acc);
    }
}

// ============ A/B precompute ================================================
// A row-major per node (zero-padded k 260..271); B in BF[k>>3][u][k&7] groups.
// Outputs prescaled by -log2e so k_pair's silu skips the scale multiply.
// unroll 8 (R7): these kernels run at ~1.1 wave/SIMD — serial load-dependent
// iterations were latency-bound; batching 16 loads in flight hides L2 latency.
__device__ __forceinline__ void ab_comp(int jl, const float* __restrict__ We1,
                                        const float* __restrict__ be1, float hval,
                                        int u, int lane,
                                        float* __restrict__ Ap, float* __restrict__ BF){
    const float* W = We1 + jl*130*E2;
    int r  = 4*lane;
    int rt = 256 + lane;
    int rtc = (lane < 4) ? rt : 256;
    F4U av; av.v = *(const float4*)(be1 + jl*E2 + r);
    F4U bv; bv.f[0]=bv.f[1]=bv.f[2]=bv.f[3]=0.0f;
    float avx = be1[jl*E2 + rtc];
    float bvx = 0.0f;
#pragma unroll 8
    for (int d = 0; d < DIMF; d++){
        float hv = __shfl(hval, d);
        F4U w1; w1.v = *(const float4*)(W + d*E2 + r);
        F4U w2; w2.v = *(const float4*)(W + (DIMF+d)*E2 + r);
#pragma unroll
        for (int i = 0; i < 4; i++){
            av.f[i] = fmaf(hv, w1.f[i], av.f[i]);
            bv.f[i] = fmaf(hv, w2.f[i], bv.f[i]);
        }
        avx = fmaf(hv, W[d*E2 + rtc], avx);
        bvx = fmaf(hv, W[(DIMF+d)*E2 + rtc], bvx);
    }
#pragma unroll
    for (int i = 0; i < 4; i++){ av.f[i] *= KNEG; bv.f[i] *= KNEG; }
    avx *= KNEG; bvx *= KNEG;
    *(float4*)(Ap + u*AS + r) = av.v;
    *(float4*)(BF + ((size_t)(lane>>1)*PADU + u)*8 + (lane&1)*4) = bv.v;
    if (lane < 16){                     // k = 256..271; zero-pad beyond 259
        int k = 256 + lane;
        float aval = (lane < 4) ? avx : 0.0f;
        float bval = (lane < 4) ? bvx : 0.0f;
        Ap[u*AS + k] = aval;
        BF[((size_t)(k>>3)*PADU + u)*8 + (k&7)] = bval;
    }
}

// ============ gather + AB(layer0) + init mi/c0/c1 ===========================
__global__ __launch_bounds__(256) void k_gab(
    const float* __restrict__ feat, const float* __restrict__ coor,
    const float* __restrict__ svals, const int* __restrict__ sidx,
    const float* __restrict__ We1, const float* __restrict__ be1,
    float* __restrict__ hc, float* __restrict__ c0, float* __restrict__ c1,
    float* __restrict__ mi, float* __restrict__ Ap, float* __restrict__ BF){
    int t = threadIdx.x; int u = blockIdx.x*4 + (t>>6); if (u >= KT) return;
    int lane = t&63;
    int l = (u<K0)?0:(u<O2)?1:2;
    int a = u - ((l==0)?0:(l==1)?O1:O2);
    int org = sidx[l*NN+a];
    float val = svals[l*NN+a];
    float hval = feat[org*DIMF+lane]*val;
    hc[u*DIMF+lane] = hval;
    if (lane < 3){ float c = coor[org*3+lane]; c0[u*4+lane]=c; c1[u*4+lane]=c; }
    if (lane == 3){ c0[u*4+3]=0.0f; c1[u*4+3]=0.0f; }
    if (lane < 20) mi[u*20+lane] = 0.0f;
    ab_comp(0, We1, be1, hval, u, lane, Ap, BF);
}

// ============ per-pair edge MLP via MFMA =====================================
// wave = (receiver u, 64-sender tile): two 32-pair MFMA acc sets.
// PRESCALE pipeline: A/B/wd carry -log2e -> p = q = -log2e*z directly;
// s' = -log2e*silu(z) vs unscaled W2f -> acc = -log2e*(acc_true + be2) via the
// k=260 bias column; Wc2P carries -ln2, msum scaled by -ln2.
// EF-SELECT (R4): stage A and A+E in LDS, lane picks base once.
// PEELED c=16 (R6): last K-iter has 4 real elems (q=0/a0 group) + bias slot.
// SKIP1 (R7): l0-tile7 has acc1's senders (480..511) entirely >= kl=460 ->
// skip shi1/acc1 MFMA (wave-uniform); acc1 stays 0, flows through masks.
// silu via sig2s rcp form (R3: beats poly form). (256,4) PROVEN optimum.
template<int DOCW>
__global__ __launch_bounds__(256, 4) void k_pair(
    int jl,
    const float* __restrict__ Ap, const float* __restrict__ BF,
    const u16* __restrict__ W2f, const u16* __restrict__ Wc1f,
    const float* __restrict__ wdP, const float* __restrict__ weP,
    const float* __restrict__ be2P, const float* __restrict__ bc1P,
    const float* __restrict__ Wc2P, const float* __restrict__ bc2,
    const float* __restrict__ cin, float* __restrict__ cout,
    float* __restrict__ mi, const int* __restrict__ sidx,
    const u64* __restrict__ ug2w){
    __shared__ __align__(16) char sWK[4*WVLDS];
    __shared__ __align__(16) char sWD[1088];
    int t = threadIdx.x;
    if (t < 68) ((float4*)sWD)[t] = *(const float4*)(wdP + jl*KPAD + 4*t);
    int wid0 = blockIdx.x*4 + (t>>6);
    int lane = t&63, n = lane&31, q = lane>>5;
    bool dead = (wid0 >= TTOT);
    int wid = dead ? (TTOT-1) : wid0;
    int l, kl, off, a, tile;
    if (wid < T0T)       { l=0; kl=K0; off=0;  a = wid>>3; tile = wid&7; }
    else if (wid < T01T) { int w = wid-T0T;  l=1; kl=K1; off=O1; a = w/NT1; tile = w - a*NT1; }
    else                 { int w = wid-T01T; l=2; kl=K2; off=O2; a = w/NT2; tile = w - a*NT2; }
    int u = off + a;
    bool skip1 = (tile*64 + 32 >= kl);   // acc1 sender block fully beyond kl
    int b0 = tile*64 + n, b1 = b0 + 32;
    int b0c = min(b0, kl-1), b1c = min(b1, kl-1);
    int ub0 = off + b0c, ub1 = off + b1c;
    int ia  = sidx[l*NN+a];
    int ib0 = sidx[l*NN+b0c], ib1 = sidx[l*NN+b1c];
    int eb0 = (int)((ug2w[ia*8 + (ib0>>6)] >> (ib0&63)) & 1ULL);
    int eb1 = (int)((ug2w[ia*8 + (ib1>>6)] >> (ib1&63)) & 1ULL);
    int sel0 = (b0 < kl) ? eb0 : 0;
    int sel1 = (b1 < kl) ? eb1 : 0;
    F4U ca;  ca.v  = ((const float4*)cin)[u];
    F4U cb0; cb0.v = ((const float4*)cin)[ub0];
    F4U cb1; cb1.v = ((const float4*)cin)[ub1];
    float tx0 = ca.f[0]-cb0.f[0], ty0 = ca.f[1]-cb0.f[1], tz0 = ca.f[2]-cb0.f[2];
    float tx1 = ca.f[0]-cb1.f[0], ty1 = ca.f[1]-cb1.f[1], tz1 = ca.f[2]-cb1.f[2];
    float dd0 = tx0*tx0 + ty0*ty0 + tz0*tz0;
    float dd1 = tx1*tx1 + ty1*ty1 + tz1*tz1;

    char* myk = sWK + (t>>6)*WVLDS;
    {   // stage A (base, [0,1088)) and A+E (edge-selected, [1088,2176))
        const float* Au = Ap + u*AS;
        const float* Ew = weP + jl*KPAD;
        F4U av; av.v = *(const float4*)(Au + 4*lane);
        F4U ev; ev.v = *(const float4*)(Ew + 4*lane);
        ((float4*)myk)[lane] = av.v;
        F4U sv;
#pragma unroll
        for (int i = 0; i < 4; i++) sv.f[i] = av.f[i] + ev.f[i];
        ((float4*)(myk + 1088))[lane] = sv.v;
        if (lane < 4){
            F4U at; at.v = *(const float4*)(Au + 256 + 4*lane);
            F4U et; et.v = *(const float4*)(Ew + 256 + 4*lane);
            ((float4*)myk)[64+lane] = at.v;
            F4U st;
#pragma unroll
            for (int i = 0; i < 4; i++) st.f[i] = at.f[i] + et.f[i];
            ((float4*)(myk + 1088))[64+lane] = st.v;
        }
    }
    __syncthreads();

    const float* pB0 = BF + ((size_t)q*PADU + ub0)*8;
    const float* pB1 = BF + ((size_t)q*PADU + ub1)*8;
    const u16*   pW  = W2f + jl*8704 + lane*8;
    const char*  pA0 = myk + sel0*1088 + q*32;
    const char*  pA1 = myk + sel1*1088 + q*32;
    const char*  pWD = sWD + q*32;

    f32x16 acc0, acc1;
#pragma unroll
    for (int r = 0; r < 16; r++){ acc0[r] = 0.0f; acc1[r] = 0.0f; }

    // prologue loads for c=0 (rotating pipeline, R9 structure)
    F4U nb0a, nb0b, nb1a, nb1b; SF nwh;
    nb0a.v = *(const float4*)(pB0);     nb0b.v = *(const float4*)(pB0 + 4);
    nb1a.v = *(const float4*)(pB1);     nb1b.v = *(const float4*)(pB1 + 4);
    nwh.i4 = *(const int4*)(pW);

    float2 DD0{dd0,dd0}, DD1{dd1,dd1};

    for (int c = 0; c < 16; c++){
        F4U b0a = nb0a, b0b = nb0b, b1a = nb1a, b1b = nb1b;
        SF  wh  = nwh;
        pB0 += 2*PADU*8; pB1 += 2*PADU*8; pW += 512;
        // unconditional prefetch for c+1 (c=15 prefetches the peeled iter's data)
        nb0a.v = *(const float4*)(pB0);     nb0b.v = *(const float4*)(pB0 + 4);
        nb1a.v = *(const float4*)(pB1);     nb1b.v = *(const float4*)(pB1 + 4);
        nwh.i4 = *(const int4*)(pW);
        F4U a00, a01, a10, a11, w0, w1;
        a00.v = *(const float4*)(pA0);     a01.v = *(const float4*)(pA0 + 16);
        a10.v = *(const float4*)(pA1);     a11.v = *(const float4*)(pA1 + 16);
        w0.v  = *(const float4*)(pWD);     w1.v  = *(const float4*)(pWD + 16);
        pA0 += 64; pA1 += 64; pWD += 64;

        SF shi0;
#pragma unroll
        for (int h = 0; h < 2; h++){
            float2 p00 = f2fma(DD0, w0.h[h], f2add(a00.h[h], b0a.h[h]));
            float2 p01 = f2fma(DD0, w1.h[h], f2add(a01.h[h], b0b.h[h]));
            float2 s00 = sig2s(p00), s01 = sig2s(p01);
            shi0.w[h]   = pk_bf16(s00.x, s00.y);
            shi0.w[2+h] = pk_bf16(s01.x, s01.y);
        }
        acc0 = __builtin_amdgcn_mfma_f32_32x32x16_bf16(shi0.v, wh.v, acc0, 0, 0, 0);
        if (!skip1){
            SF shi1;
#pragma unroll
            for (int h = 0; h < 2; h++){
                float2 p10 = f2fma(DD1, w0.h[h], f2add(a10.h[h], b1a.h[h]));
                float2 p11 = f2fma(DD1, w1.h[h], f2add(a11.h[h], b1b.h[h]));
                float2 s10 = sig2s(p10), s11 = sig2s(p11);
                shi1.w[h]   = pk_bf16(s10.x, s10.y);
                shi1.w[2+h] = pk_bf16(s11.x, s11.y);
            }
            acc1 = __builtin_amdgcn_mfma_f32_32x32x16_bf16(shi1.v, wh.v, acc1, 0, 0, 0);
        }
    }

    {   // peeled c=16: real hidden units only k=256..259 (q=0, a0 group);
        // k=260 is the bias column (s'=1.0); all else pad-zero.
        F4U b0a = nb0a, b1a = nb1a;
        SF  wh  = nwh;
        F4U a00, a10, w0;
        a00.v = *(const float4*)(pA0);
        a10.v = *(const float4*)(pA1);
        w0.v  = *(const float4*)(pWD);
        bool q0 = (q == 0);
        SF shi0;
#pragma unroll
        for (int h = 0; h < 2; h++){
            float2 p00 = f2fma(DD0, w0.h[h], f2add(a00.h[h], b0a.h[h]));
            float2 s00 = sig2s(p00);
            shi0.w[h] = q0 ? pk_bf16(s00.x, s00.y) : 0u;
        }
        shi0.w[2] = q0 ? 0x3F80u : 0u;   // e4 = k260 = 1.0 (bf16), e5 = 0
        shi0.w[3] = 0u;
        acc0 = __builtin_amdgcn_mfma_f32_32x32x16_bf16(shi0.v, wh.v, acc0, 0, 0, 0);
        if (!skip1){
            SF shi1;
#pragma unroll
            for (int h = 0; h < 2; h++){
                float2 p10 = f2fma(DD1, w0.h[h], f2add(a10.h[h], b1a.h[h]));
                float2 s10 = sig2s(p10);
                shi1.w[h] = q0 ? pk_bf16(s10.x, s10.y) : 0u;
            }
            shi1.w[2] = q0 ? 0x3F80u : 0u;
            shi1.w[3] = 0u;
            acc1 = __builtin_amdgcn_mfma_f32_32x32x16_bf16(shi1.v, wh.v, acc1, 0, 0, 0);
        }
    }

    // ---- m = silu'(acc) (bias already in acc via k=260 column); paired sig2s;
    //      masked m_i sum (x -ln2); (DOCW) repack to LDS bf16.
    //      skip1 waves: acc1 == 0 -> s1 == 0 -> masked rows get 0 as required.
    u16* mlds = (u16*)myk;               // overwrites A stage (done with it)
    float msum = 0.0f;
#pragma unroll
    for (int r = 0; r < 16; r += 2){
        int row = (r&3) + 8*(r>>2) + 4*q;
        float2 s0 = sig2s(float2{acc0[r], acc0[r+1]});
        float2 s1 = sig2s(float2{acc1[r], acc1[r+1]});
        float m00 = (tile*64 + row     < kl) ? s0.x : 0.0f;
        float m01 = (tile*64 + row + 1 < kl) ? s0.y : 0.0f;
        float m10 = (tile*64 + 32 + row     < kl) ? s1.x : 0.0f;
        float m11 = (tile*64 + 32 + row + 1 < kl) ? s1.y : 0.0f;
        msum += (m00 + m01) + (m10 + m11);
        if (DOCW){
            mlds[row*MSTR + n]      = bf16_rne(m00);
            mlds[(row+1)*MSTR + n]  = bf16_rne(m01);
            mlds[(row+32)*MSTR + n] = bf16_rne(m10);
            mlds[(row+33)*MSTR + n] = bf16_rne(m11);
        }
    }
    msum += __shfl_xor(msum, 32);
    if (!dead && lane < MD) atomicAdd(&mi[u*20 + lane], msum * LN2N);

    if (DOCW){
        lgkm_wait();
        const char* mb = (const char*)mlds;
        float gx = 0.0f, gy = 0.0f, gz = 0.0f;
        float bc2v = bc2[jl];
#pragma unroll
        for (int S = 0; S < 2; S++){
            SF af0, af1;
            af0.i4 = *(const int4*)(mb + (S*32+n)*(MSTR*2) + q*16);
            af1.i4 = *(const int4*)(mb + (S*32+n)*(MSTR*2) + 32 + q*16);
            float cwp[16];
#pragma unroll
            for (int r = 0; r < 16; r++) cwp[r] = 0.0f;
            for (int T = 0; T < 3; T++){
                SF bb0, bb1;
                bb0.i4 = *(const int4*)(Wc1f + jl*3072 + T*1024 +       lane*8);
                bb1.i4 = *(const int4*)(Wc1f + jl*3072 + T*1024 + 512 + lane*8);
                f32x16 p2;
#pragma unroll
                for (int r = 0; r < 16; r++) p2[r] = 0.0f;
                p2 = __builtin_amdgcn_mfma_f32_32x32x16_bf16(af0.v, bb0.v, p2, 0, 0, 0);
                p2 = __builtin_amdgcn_mfma_f32_32x32x16_bf16(af1.v, bb1.v, p2, 0, 0, 0);
                float bc1v = bc1P[jl*96 + T*32 + n];
                float wc2v = Wc2P[jl*96 + T*32 + n];
#pragma unroll
                for (int r = 0; r < 16; r++)
                    cwp[r] = fmaf(silups(p2[r] + bc1v), wc2v, cwp[r]);
            }
#pragma unroll
            for (int r = 0; r < 16; r++){
                int row  = (r&3) + 8*(r>>2) + 4*q + S*32;
                int brow = tile*64 + row;
                F4U cbr; cbr.v = ((const float4*)cin)[off + min(brow, kl-1)];
                float cw = cwp[r] + ((n == 0) ? bc2v : 0.0f);
                cw = (brow < kl) ? cw : 0.0f;
                gx = fmaf(cw, ca.f[0]-cbr.f[0], gx);
                gy = fmaf(cw, ca.f[1]-cbr.f[1], gy);
                gz = fmaf(cw, ca.f[2]-cbr.f[2], gz);
            }
        }
#pragma unroll
        for (int s = 1; s < 64; s <<= 1){
            gx += __shfl_xor(gx, s); gy += __shfl_xor(gy, s); gz += __shfl_xor(gz, s);
        }
        if (!dead && lane == 0){
            atomicAdd(&cout[u*4+0], gx);
            atomicAdd(&cout[u*4+1], gy);
            atomicAdd(&cout[u*4+2], gz);
        }
    }
}

// ============ node MLP + (optionally) AB for next layer + inits ==============
// Final layer (donext==0): fused scatter-max into out via u32 atomicMax
// (valid: hn >= 0 after relu; out zero-initialized in k_pre).
// unroll 8 (R7): latency fix — see ab_comp comment.
__global__ __launch_bounds__(256) void k_nodeab(
    int jl, int donext, int docopy,
    const float* __restrict__ Wn1, const float* __restrict__ bn1,
    const float* __restrict__ Wn2, const float* __restrict__ bn2,
    const float* __restrict__ We1, const float* __restrict__ be1,
    float* __restrict__ hc, float* __restrict__ mi,
    const float* __restrict__ ccur, float* __restrict__ cnext,
    float* __restrict__ Ap, float* __restrict__ BF,
    const int* __restrict__ sidx, float* __restrict__ outv){
    int t = threadIdx.x; int u = blockIdx.x*4 + (t>>6); if (u >= KT) return;
    int lane = t&63;
    float hval = hc[u*DIMF+lane];
    float mval = (lane < MD) ? mi[u*20+lane] : 0.0f;
    const float* W1 = Wn1 + jl*(DIMF+MD)*NH1;
    float v0 = bn1[jl*NH1+lane], v1 = bn1[jl*NH1+lane+64];
#pragma unroll 8
    for (int d = 0; d < DIMF; d++){
        float x = __shfl(hval, d);
        v0 = fmaf(x, W1[d*NH1+lane],    v0);
        v1 = fmaf(x, W1[d*NH1+lane+64], v1);
    }
#pragma unroll
    for (int d = 0; d < MD; d++){
        float x = __shfl(mval, d);
        v0 = fmaf(x, W1[(DIMF+d)*NH1+lane],    v0);
        v1 = fmaf(x, W1[(DIMF+d)*NH1+lane+64], v1);
    }
    float s0 = silups(v0 * KNEG) * LN2N, s1 = silups(v1 * KNEG) * LN2N;
    const float* W2 = Wn2 + jl*NH1*DIMF;
    float h = bn2[jl*DIMF+lane];
#pragma unroll 8
    for (int i = 0; i < 64; i++) h = fmaf(__shfl(s0, i), W2[i*DIMF+lane], h);
#pragma unroll 8
    for (int i = 0; i < 64; i++) h = fmaf(__shfl(s1, i), W2[(64+i)*DIMF+lane], h);
    float hn = fmaxf(0.0f, fmaf(2.0f, hval, h));
    hc[u*DIMF+lane] = hn;
    if (donext){
        if (lane < 20) mi[u*20+lane] = 0.0f;
        if (docopy && lane < 4) cnext[u*4+lane] = ccur[u*4+lane];
        ab_comp(jl+1, We1, be1, hn, u, lane, Ap, BF);
    } else {
        int l2 = (u<K0)?0:(u<O2)?1:2;
        int a2 = u - ((l2==0)?0:(l2==1)?O1:O2);
        int org = sidx[l2*NN+a2];
        atomicMax((u32*)&outv[org*DIMF+lane], __float_as_uint(hn));
    }
}

extern "C" void kernel_launch(void* const* d_in, const int* in_sizes, int n_in,
                              void* d_out, int out_size, void* d_ws, size_t ws_size,
                              hipStream_t stream) {
    (void)in_sizes; (void)n_in; (void)out_size; (void)ws_size;
    const float* feat = (const float*)d_in[0];
    const float* coor = (const float*)d_in[1];
    const float* edge = (const float*)d_in[2];
    const float* We1  = (const float*)d_in[3];
    const float* be1  = (const float*)d_in[4];
    const float* We2  = (const float*)d_in[5];
    const float* be2  = (const float*)d_in[6];
    const float* Wc1  = (const float*)d_in[7];
    const float* bc1  = (const float*)d_in[8];
    const float* Wc2  = (const float*)d_in[9];
    const float* bc2  = (const float*)d_in[10];
    const float* Wn1  = (const float*)d_in[11];
    const float* bn1  = (const float*)d_in[12];
    const float* Wn2  = (const float*)d_in[13];
    const float* bn2  = (const float*)d_in[14];
    const float* wp   = (const float*)d_in[15];
    const float* bp   = (const float*)d_in[16];
    float* out = (float*)d_out;

    char* wsb = (char*)d_ws;
    u64*   ugw    = (u64*)  (wsb + 0);         // 32768
    u64*   ug2w   = (u64*)  (wsb + 32768);     // 32768
    float* scores = (float*)(wsb + 65536);     // 6144
    float* svals  = (float*)(wsb + 71680);     // 6144
    int*   sidx   = (int*)  (wsb + 77824);     // 6144
    int*   rev    = (int*)  (wsb + 83968);     // 6144
    float* c0     = (float*)(wsb + 90112);     // 18432
    float* c1     = (float*)(wsb + 108544);    // 18432
    float* mi     = (float*)(wsb + 126976);    // 90112
    float* hc     = (float*)(wsb + 217088);    // 288256
    float* Ap     = (float*)(wsb + 505344);    // 1224192
    float* BF     = (float*)(wsb + 1729536);   // 1253376 (34*1152*8*4)
    u16*   W2f    = (u16*)  (wsb + 2982912);   // 52224 (3*17*512*2, hi-only)
    u16*   Wc1f   = (u16*)  (wsb + 3087360);   // 18432
    float* wdP    = (float*)(wsb + 3105792);   // 3328
    float* weP    = (float*)(wsb + 3109120);   // 3328
    float* be2P   = (float*)(wsb + 3112448);   // 384
    float* bc1P   = (float*)(wsb + 3112832);   // 1152
    float* Wc2P   = (float*)(wsb + 3113984);   // 1152  (end ~3.12 MB)

    k_pre<<<425, 256, 0, stream>>>(edge, feat, wp, bp, We2, Wc1, We1, be2, bc1, Wc2,
                                   ugw, scores, W2f, Wc1f,
                                   wdP, weP, be2P, bc1P, Wc2P, ug2w, out);
    k_sortug2<<<67, 512, 0, stream>>>(scores, ugw, svals, sidx, rev, ug2w);
    k_gab<<<282, 256, 0, stream>>>(feat, coor, svals, sidx, We1, be1,
                                   hc, c0, c1, mi, Ap, BF);
    // layer 0: cin=c0, cout=c1
    k_pair<1><<<PBLK, 256, 0, stream>>>(0, Ap, BF, W2f, Wc1f,
                                        wdP, weP, be2P, bc1P, Wc2P, bc2,
                                        c0, c1, mi, sidx, ug2w);
    k_nodeab<<<282, 256, 0, stream>>>(0, 1, 1, Wn1, bn1, Wn2, bn2, We1, be1,
                                      hc, mi, c1, c0, Ap, BF, sidx, out);
    // layer 1: cin=c1, cout=c0 (pre-initialized to c1 by k_nodeab)
    k_pair<1><<<PBLK, 256, 0, stream>>>(1, Ap, BF, W2f, Wc1f,
                                        wdP, weP, be2P, bc1P, Wc2P, bc2,
                                        c1, c0, mi, sidx, ug2w);
    k_nodeab<<<282, 256, 0, stream>>>(1, 1, 0, Wn1, bn1, Wn2, bn2, We1, be1,
                                      hc, mi, c0, c1, Ap, BF, sidx, out);
    // layer 2: coords output unused -> no coord MLP instantiation
    k_pair<0><<<PBLK, 256, 0, stream>>>(2, Ap, BF, W2f, Wc1f,
                                        wdP, weP, be2P, bc1P, Wc2P, bc2,
                                        c0, c1, mi, sidx, ug2w);
    // final: node MLP + fused scatter-max into out (replaces k_final)
    k_nodeab<<<282, 256, 0, stream>>>(2, 0, 0, Wn1, bn1, Wn2, bn2, We1, be1,
                                      hc, mi, c0, c1, Ap, BF, sidx, out);
}

// Round 9
// 347.127 us; speedup vs baseline: 1.0012x; 1.0012x over previous
//
// R9 = R8-fix: R8's container crash was a REAL kernel fault — MSTR 38 made the
// coord-MLP ds_read_b128 rows misaligned (stride 76 B; b128 needs 16 B align).
// Keep MSTR=40/WVLDS=5120 (aligned, proven) and drop ONLY sWD: block LDS =
// 4*5120 = 20480 B exactly -> 8 blocks/CU, whole 1841-block grid co-resident.
#include <hip/hip_runtime.h>
#include <hip/hip_bf16.h>

typedef unsigned long long u64;
typedef unsigned int u32;
typedef unsigned short u16;

#define NN   512
#define DIMF 64
#define E2   260
#define KPAD 272
#define MD   17
#define MH   68
#define NH1  128
#define K0   460
#define K1   358
#define K2   307
#define KT   1125
#define O1   460
#define O2   818
#define PADU 1152
#define AS   272
// 64-sender tiles per receiver, one wave each (2 MFMA acc sets of 32)
#define NT0  8
#define NT1  6
#define NT2  5
#define T0T   (K0*NT0)          // 3680
#define T01T  (T0T + K1*NT1)    // 5828
#define TTOT  (T01T + K2*NT2)   // 7363
#define PBLK  ((TTOT+3)/4)      // 1841
#define MSTR  40                // u16 stride of m-repack rows (80 B: 16B-aligned
                                // rows for ds_read_b128; R6-proven. NOT 38!)
#define WVLDS 5120              // per-wave LDS; 4*5120 = 20480 B/block exactly

// prescale constants: sigma(z) = rcp(1 + exp2(q)), q = -log2(e)*z; ln2*log2e == 1
#define KNEG  (-1.4426950408889634f)
#define LN2N  (-0.6931471805599453f)

typedef __attribute__((ext_vector_type(8)))  short short8;
typedef __attribute__((ext_vector_type(16))) float f32x16;

union SF  { int4 i4; u16 us[8]; u32 w[4]; short8 v; };
union F4U { float4 v; float2 h[2]; float f[4]; u32 w[4]; };

__device__ __forceinline__ float fast_exp2(float x){
#if __has_builtin(__builtin_amdgcn_exp2f)
    return __builtin_amdgcn_exp2f(x);
#else
    return __expf(x * 0.6931471805599453f);
#endif
}
__device__ __forceinline__ float fast_rcp(float x){
#if __has_builtin(__builtin_amdgcn_rcpf)
    return __builtin_amdgcn_rcpf(x);
#else
    return __fdividef(1.0f, x);
#endif
}
// prescaled silu: input q = -log2e * z, returns -log2e * silu(z)
__device__ __forceinline__ float silups(float q){
    return q * fast_rcp(1.0f + fast_exp2(q));
}
__device__ __forceinline__ float sigf(float x){
    return fast_rcp(1.0f + fast_exp2(x * KNEG));
}
__device__ __forceinline__ u16 bf16_rne(float f){
    u32 u = __float_as_uint(f);
    u += 0x7FFFu + ((u >> 16) & 1u);
    return (u16)(u >> 16);
}
__device__ __forceinline__ float bf16f(u16 h){
    return __uint_as_float(((u32)h) << 16);
}
// packed RNE bf16x2 (v_cvt_pk_bf16_f32 on gfx950)
__device__ __forceinline__ u32 pk_bf16(float x, float y){
    float2 f2; f2.x = x; f2.y = y;
    __hip_bfloat162 h = __float22bfloat162_rn(f2);
    union { __hip_bfloat162 b; u32 u; } cv; cv.b = h;
    return cv.u;
}
__device__ __forceinline__ void lgkm_wait(){
#if __has_builtin(__builtin_amdgcn_s_waitcnt)
    __builtin_amdgcn_s_waitcnt(0xC07F);   // lgkmcnt(0)
#endif
}
// packed float2 helpers (SLP-friendly -> v_pk_fma_f32 / v_pk_add_f32 / v_pk_mul_f32)
__device__ __forceinline__ float2 f2add(float2 a, float2 b){ return float2{a.x+b.x, a.y+b.y}; }
__device__ __forceinline__ float2 f2mul(float2 a, float2 b){ return float2{a.x*b.x, a.y*b.y}; }
__device__ __forceinline__ float2 f2fma(float2 a, float2 b, float2 c){
    return float2{fmaf(a.x,b.x,c.x), fmaf(a.y,b.y,c.y)};
}
// prescaled paired silu, rcp form. R3 post-mortem: this (4 trans + 2 pk) BEATS
// the deg-4 poly form (2 trans + 8 pk) on gfx950 — trans ops issue cheaply;
// total VALU slots dominate. Do NOT re-introduce sig2p.
__device__ __forceinline__ float2 sig2s(float2 q){
    float ex = fast_exp2(q.x), ey = fast_exp2(q.y);
    float2 den = f2add(float2{1.0f, 1.0f}, float2{ex, ey});
    float rx = fast_rcp(den.x), ry = fast_rcp(den.y);
    return f2mul(q, float2{rx, ry});
}

// ============ fused prep: ug bitmasks + pooling scores + weight fragments ===
__global__ __launch_bounds__(256) void k_pre(
    const float* __restrict__ edge, const float* __restrict__ feat,
    const float* __restrict__ wp, const float* __restrict__ bp,
    const float* __restrict__ We2, const float* __restrict__ Wc1,
    const float* __restrict__ We1, const float* __restrict__ be2,
    const float* __restrict__ bc1, const float* __restrict__ Wc2,
    u64* __restrict__ ugw, float* __restrict__ scores,
    u16* __restrict__ W2f, u16* __restrict__ Wc1f,
    float* __restrict__ wdP, float* __restrict__ weP, float* __restrict__ be2P,
    float* __restrict__ bc1P, float* __restrict__ Wc2P, u64* __restrict__ ug2w,
    float* __restrict__ outz){
    int blk = blockIdx.x, t = threadIdx.x;
    if (blk < 128){                      // ug row bitmasks, 4 rows/block
        int i = blk*4 + (t>>6); int lane = t&63;
        const float* row = edge + (size_t)i*NN;
        for (int w = 0; w < 8; w++){
            u64 m = __ballot(row[w*64+lane] != 0.0f);
            if (lane == 0) ugw[i*8+w] = m;
        }
        return;
    }
    if (blk < 134){                      // pooling scores (float4 dot)
        int gid = (blk-128)*256 + t; if (gid >= 3*NN) return;
        int l = gid>>9, n = gid&511;
        const float4* fr = (const float4*)(feat + n*DIMF);
        const float4* wr = (const float4*)(wp + l*DIMF);
        float s = bp[l];
        for (int d = 0; d < 16; d++){
            float4 f = fr[d], w = wr[d];
            s = fmaf(f.x, w.x, s); s = fmaf(f.y, w.y, s);
            s = fmaf(f.z, w.z, s); s = fmaf(f.w, w.w, s);
        }
        scores[gid] = sigf(s);
        return;
    }
    int idx = (blk-134)*256 + t;
    if (idx < 26112){                    // We2 frags hi-only: [jl][c17][lane64][8]
        // k==260 pad slot carries the prescaled be2 bias column (s'[260]==1).
        int e = idx&7, lane = (idx>>3)&63, c = (idx>>9)%17, jl = idx/8704;
        int q = lane>>5, nn = lane&31;
        int k = c*16 + q*8 + e;
        float v = (k < E2 && nn < MD) ? We2[jl*E2*MD + k*MD + nn]
                : (k == 260 && nn < MD) ? be2[jl*MD+nn]*KNEG : 0.0f;
        W2f[idx] = bf16_rne(v);
        return;
    }
    idx -= 26112;
    if (idx < 9216){                     // Wc1 frags: [jl][T3][c2][lane][8]
        int e = idx & 7, lane = (idx>>3)&63, c2 = (idx>>9)&1, T = (idx>>10)%3, jl = idx/3072;
        int q = lane>>5, nn = lane&31;
        int o = c2*16 + q*8 + e, h = T*32 + nn;
        float v = (o < MD && h < MH) ? Wc1[jl*MD*MH + o*MH + h] : 0.0f;
        Wc1f[idx] = bf16_rne(v);
        return;
    }
    idx -= 9216;
    if (idx < 816){ int jl = idx/KPAD, k = idx%KPAD;
        wdP[idx] = (k < E2) ? We1[jl*130*E2 + 128*E2 + k]*KNEG : 0.0f; return; }
    idx -= 816;
    if (idx < 816){ int jl = idx/KPAD, k = idx%KPAD;
        weP[idx] = (k < E2) ? We1[jl*130*E2 + 129*E2 + k]*KNEG : 0.0f; return; }
    idx -= 816;
    if (idx < 96){ int jl = idx/32, o = idx%32;
        be2P[idx] = (o < MD) ? be2[jl*MD+o]*KNEG : 0.0f; return; }
    idx -= 96;
    if (idx < 288){ int jl = idx/96, h = idx%96;
        bc1P[idx] = (h < MH) ? bc1[jl*MH+h]*KNEG : 0.0f; return; }
    idx -= 288;
    if (idx < 288){ int jl = idx/96, h = idx%96;
        Wc2P[idx] = (h < MH) ? Wc2[jl*MH+h]*LN2N : 0.0f; return; }
    idx -= 288;
    if (idx < 4096){ ug2w[idx] = 0ULL; return; }   // zero for k_sortug2's atomicOr
    idx -= 4096;
    if (idx < NN*DIMF){ outz[idx] = 0.0f; return; } // zero out for fused atomicMax scatter
}

// ============ fused: bitonic sort (3 blocks) + ug2 bitset matmul (64 blocks) =
// sort: shfl-register bitonic for jj<=32 (39 of 45 rounds barrier-free)
__global__ __launch_bounds__(512) void k_sortug2(
    const float* __restrict__ scores, const u64* __restrict__ ugw,
    float* __restrict__ svals, int* __restrict__ sidx, int* __restrict__ rev,
    u64* __restrict__ ug2w){
    int blk = blockIdx.x, t = threadIdx.x;
    if (blk < 3){
        int l = blk;
        __shared__ float sk[NN];
        __shared__ int   si[NN];
        float key = scores[l*NN+t]; int idx = t;
        rev[l*NN+t] = -1;
        for (int k = 2; k <= NN; k <<= 1){
            for (int jj = k>>1; jj > 0; jj >>= 1){
                float kb; int ib;
                if (jj >= 64){
                    sk[t] = key; si[t] = idx;
                    __syncthreads();
                    kb = sk[t^jj]; ib = si[t^jj];
                    __syncthreads();
                } else {
                    kb = __shfl_xor(key, jj);
                    ib = __shfl_xor(idx, jj);
                }
                bool aFirst = (key > kb) || (key == kb && idx < ib);
                bool down   = ((t & k) == 0);
                bool lower  = ((t & jj) == 0);
                bool keep   = (aFirst == (lower == down));
                key = keep ? key : kb;
                idx = keep ? idx : ib;
            }
        }
        svals[l*NN+t] = key; sidx[l*NN+t] = idx;
        int kcnt = (l==0)?K0:(l==1)?K1:K2;
        if (t < kcnt) rev[l*NN + idx] = t;
    } else {
        // (i, w, kc): row i, out-word w, row-mask word kc. Iterate SET BITS only.
        int gid = (blk-3)*512 + t;       // 32768 total
        int i  = gid >> 6;
        int w  = (gid >> 3) & 7;
        int kc = gid & 7;
        u64 rm = ugw[i*8 + kc];
        u64 acc = 0;
        int base = kc*64;
        while (rm){
            int k2 = __builtin_ctzll(rm);
            rm &= rm - 1;
            acc |= ugw[(base + k2)*8 + w];
        }
        if (acc) atomicOr(&ug2w[i*8 + w], acc);
    }
}

// ============ A/B precompute ================================================
// A row-major per node (zero-padded k 260..271); B in BF[k>>3][u][k&7] groups.
// Outputs prescaled by -log2e so k_pair's silu skips the scale multiply.
// NOTE (R7/R8): do NOT unroll the d-loop — 8x unroll spilled (16 float4 load
// dests in flight) and cost +10us across k_gab/k_nodeab.
__device__ __forceinline__ void ab_comp(int jl, const float* __restrict__ We1,
                                        const float* __restrict__ be1, float hval,
                                        int u, int lane,
                                        float* __restrict__ Ap, float* __restrict__ BF){
    const float* W = We1 + jl*130*E2;
    int r  = 4*lane;
    int rt = 256 + lane;
    int rtc = (lane < 4) ? rt : 256;
    F4U av; av.v = *(const float4*)(be1 + jl*E2 + r);
    F4U bv; bv.f[0]=bv.f[1]=bv.f[2]=bv.f[3]=0.0f;
    float avx = be1[jl*E2 + rtc];
    float bvx = 0.0f;
    for (int d = 0; d < DIMF; d++){
        float hv = __shfl(hval, d);
        F4U w1; w1.v = *(const float4*)(W + d*E2 + r);
        F4U w2; w2.v = *(const float4*)(W + (DIMF+d)*E2 + r);
#pragma unroll
        for (int i = 0; i < 4; i++){
            av.f[i] = fmaf(hv, w1.f[i], av.f[i]);
            bv.f[i] = fmaf(hv, w2.f[i], bv.f[i]);
        }
        avx = fmaf(hv, W[d*E2 + rtc], avx);
        bvx = fmaf(hv, W[(DIMF+d)*E2 + rtc], bvx);
    }
#pragma unroll
    for (int i = 0; i < 4; i++){ av.f[i] *= KNEG; bv.f[i] *= KNEG; }
    avx *= KNEG; bvx *= KNEG;
    *(float4*)(Ap + u*AS + r) = av.v;
    *(float4*)(BF + ((size_t)(lane>>1)*PADU + u)*8 + (lane&1)*4) = bv.v;
    if (lane < 16){                     // k = 256..271; zero-pad beyond 259
        int k = 256 + lane;
        float aval = (lane < 4) ? avx : 0.0f;
        float bval = (lane < 4) ? bvx : 0.0f;
        Ap[u*AS + k] = aval;
        BF[((size_t)(k>>3)*PADU + u)*8 + (k&7)] = bval;
    }
}

// ============ gather + AB(layer0) + init mi/c0/c1 ===========================
__global__ __launch_bounds__(256) void k_gab(
    const float* __restrict__ feat, const float* __restrict__ coor,
    const float* __restrict__ svals, const int* __restrict__ sidx,
    const float* __restrict__ We1, const float* __restrict__ be1,
    float* __restrict__ hc, float* __restrict__ c0, float* __restrict__ c1,
    float* __restrict__ mi, float* __restrict__ Ap, float* __restrict__ BF){
    int t = threadIdx.x; int u = blockIdx.x*4 + (t>>6); if (u >= KT) return;
    int lane = t&63;
    int l = (u<K0)?0:(u<O2)?1:2;
    int a = u - ((l==0)?0:(l==1)?O1:O2);
    int org = sidx[l*NN+a];
    float val = svals[l*NN+a];
    float hval = feat[org*DIMF+lane]*val;
    hc[u*DIMF+lane] = hval;
    if (lane < 3){ float c = coor[org*3+lane]; c0[u*4+lane]=c; c1[u*4+lane]=c; }
    if (lane == 3){ c0[u*4+3]=0.0f; c1[u*4+3]=0.0f; }
    if (lane < 20) mi[u*20+lane] = 0.0f;
    ab_comp(0, We1, be1, hval, u, lane, Ap, BF);
}

// ============ per-pair edge MLP via MFMA =====================================
// wave = (receiver u, 64-sender tile): two 32-pair MFMA acc sets.
// PRESCALE pipeline: A/B/wd carry -log2e -> p = q = -log2e*z directly;
// s' = -log2e*silu(z) vs unscaled W2f -> acc = -log2e*(acc_true + be2) via the
// k=260 bias column; Wc2P carries -ln2, msum scaled by -ln2.
// EF-SELECT (R4): stage A and A+E in LDS, lane picks base once.
// PEELED c=16 (R6): last K-iter has 4 real elems (q=0/a0 group) + bias slot.
// SKIP1 (R7): tiles whose acc1 sender block is fully >= kl skip shi1/acc1.
// LDS DIET (R9): wd read from global (L1-hot, 1088B); MSTR stays 40 (aligned!)
// -> block LDS 4*5120 = 20480B -> 8 blocks/CU, whole grid co-resident.
template<int DOCW>
__global__ __launch_bounds__(256, 4) void k_pair(
    int jl,
    const float* __restrict__ Ap, const float* __restrict__ BF,
    const u16* __restrict__ W2f, const u16* __restrict__ Wc1f,
    const float* __restrict__ wdP, const float* __restrict__ weP,
    const float* __restrict__ be2P, const float* __restrict__ bc1P,
    const float* __restrict__ Wc2P, const float* __restrict__ bc2,
    const float* __restrict__ cin, float* __restrict__ cout,
    float* __restrict__ mi, const int* __restrict__ sidx,
    const u64* __restrict__ ug2w){
    __shared__ __align__(16) char sWK[4*WVLDS];
    int t = threadIdx.x;
    int wid0 = blockIdx.x*4 + (t>>6);
    int lane = t&63, n = lane&31, q = lane>>5;
    bool dead = (wid0 >= TTOT);
    int wid = dead ? (TTOT-1) : wid0;
    int l, kl, off, a, tile;
    if (wid < T0T)       { l=0; kl=K0; off=0;  a = wid>>3; tile = wid&7; }
    else if (wid < T01T) { int w = wid-T0T;  l=1; kl=K1; off=O1; a = w/NT1; tile = w - a*NT1; }
    else                 { int w = wid-T01T; l=2; kl=K2; off=O2; a = w/NT2; tile = w - a*NT2; }
    int u = off + a;
    bool skip1 = (tile*64 + 32 >= kl);   // acc1 sender block fully beyond kl
    int b0 = tile*64 + n, b1 = b0 + 32;
    int b0c = min(b0, kl-1), b1c = min(b1, kl-1);
    int ub0 = off + b0c, ub1 = off + b1c;
    int ia  = sidx[l*NN+a];
    int ib0 = sidx[l*NN+b0c], ib1 = sidx[l*NN+b1c];
    int eb0 = (int)((ug2w[ia*8 + (ib0>>6)] >> (ib0&63)) & 1ULL);
    int eb1 = (int)((ug2w[ia*8 + (ib1>>6)] >> (ib1&63)) & 1ULL);
    int sel0 = (b0 < kl) ? eb0 : 0;
    int sel1 = (b1 < kl) ? eb1 : 0;
    F4U ca;  ca.v  = ((const float4*)cin)[u];
    F4U cb0; cb0.v = ((const float4*)cin)[ub0];
    F4U cb1; cb1.v = ((const float4*)cin)[ub1];
    float tx0 = ca.f[0]-cb0.f[0], ty0 = ca.f[1]-cb0.f[1], tz0 = ca.f[2]-cb0.f[2];
    float tx1 = ca.f[0]-cb1.f[0], ty1 = ca.f[1]-cb1.f[1], tz1 = ca.f[2]-cb1.f[2];
    float dd0 = tx0*tx0 + ty0*ty0 + tz0*tz0;
    float dd1 = tx1*tx1 + ty1*ty1 + tz1*tz1;

    char* myk = sWK + (t>>6)*WVLDS;
    {   // stage A (base, [0,1088)) and A+E (edge-selected, [1088,2176))
        const float* Au = Ap + u*AS;
        const float* Ew = weP + jl*KPAD;
        F4U av; av.v = *(const float4*)(Au + 4*lane);
        F4U ev; ev.v = *(const float4*)(Ew + 4*lane);
        ((float4*)myk)[lane] = av.v;
        F4U sv;
#pragma unroll
        for (int i = 0; i < 4; i++) sv.f[i] = av.f[i] + ev.f[i];
        ((float4*)(myk + 1088))[lane] = sv.v;
        if (lane < 4){
            F4U at; at.v = *(const float4*)(Au + 256 + 4*lane);
            F4U et; et.v = *(const float4*)(Ew + 256 + 4*lane);
            ((float4*)myk)[64+lane] = at.v;
            F4U st;
#pragma unroll
            for (int i = 0; i < 4; i++) st.f[i] = at.f[i] + et.f[i];
            ((float4*)(myk + 1088))[64+lane] = st.v;
        }
    }
    __syncthreads();

    const float* pB0 = BF + ((size_t)q*PADU + ub0)*8;
    const float* pB1 = BF + ((size_t)q*PADU + ub1)*8;
    const u16*   pW  = W2f + jl*8704 + lane*8;
    const char*  pA0 = myk + sel0*1088 + q*32;
    const char*  pA1 = myk + sel1*1088 + q*32;
    const char*  pWD = (const char*)(wdP + jl*KPAD) + q*32;   // global, L1-hot

    f32x16 acc0, acc1;
#pragma unroll
    for (int r = 0; r < 16; r++){ acc0[r] = 0.0f; acc1[r] = 0.0f; }

    // prologue loads for c=0 (rotating pipeline, R9 structure)
    F4U nb0a, nb0b, nb1a, nb1b; SF nwh;
    nb0a.v = *(const float4*)(pB0);     nb0b.v = *(const float4*)(pB0 + 4);
    nb1a.v = *(const float4*)(pB1);     nb1b.v = *(const float4*)(pB1 + 4);
    nwh.i4 = *(const int4*)(pW);

    float2 DD0{dd0,dd0}, DD1{dd1,dd1};

    for (int c = 0; c < 16; c++){
        F4U b0a = nb0a, b0b = nb0b, b1a = nb1a, b1b = nb1b;
        SF  wh  = nwh;
        pB0 += 2*PADU*8; pB1 += 2*PADU*8; pW += 512;
        // unconditional prefetch for c+1 (c=15 prefetches the peeled iter's data)
        nb0a.v = *(const float4*)(pB0);     nb0b.v = *(const float4*)(pB0 + 4);
        nb1a.v = *(const float4*)(pB1);     nb1b.v = *(const float4*)(pB1 + 4);
        nwh.i4 = *(const int4*)(pW);
        F4U a00, a01, a10, a11, w0, w1;
        a00.v = *(const float4*)(pA0);     a01.v = *(const float4*)(pA0 + 16);
        a10.v = *(const float4*)(pA1);     a11.v = *(const float4*)(pA1 + 16);
        w0.v  = *(const float4*)(pWD);     w1.v  = *(const float4*)(pWD + 16);
        pA0 += 64; pA1 += 64; pWD += 64;

        SF shi0;
#pragma unroll
        for (int h = 0; h < 2; h++){
            float2 p00 = f2fma(DD0, w0.h[h], f2add(a00.h[h], b0a.h[h]));
            float2 p01 = f2fma(DD0, w1.h[h], f2add(a01.h[h], b0b.h[h]));
            float2 s00 = sig2s(p00), s01 = sig2s(p01);
            shi0.w[h]   = pk_bf16(s00.x, s00.y);
            shi0.w[2+h] = pk_bf16(s01.x, s01.y);
        }
        acc0 = __builtin_amdgcn_mfma_f32_32x32x16_bf16(shi0.v, wh.v, acc0, 0, 0, 0);
        if (!skip1){
            SF shi1;
#pragma unroll
            for (int h = 0; h < 2; h++){
                float2 p10 = f2fma(DD1, w0.h[h], f2add(a10.h[h], b1a.h[h]));
                float2 p11 = f2fma(DD1, w1.h[h], f2add(a11.h[h], b1b.h[h]));
                float2 s10 = sig2s(p10), s11 = sig2s(p11);
                shi1.w[h]   = pk_bf16(s10.x, s10.y);
                shi1.w[2+h] = pk_bf16(s11.x, s11.y);
            }
            acc1 = __builtin_amdgcn_mfma_f32_32x32x16_bf16(shi1.v, wh.v, acc1, 0, 0, 0);
        }
    }

    {   // peeled c=16: real hidden units only k=256..259 (q=0, a0 group);
        // k=260 is the bias column (s'=1.0); all else pad-zero.
        F4U b0a = nb0a, b1a = nb1a;
        SF  wh  = nwh;
        F4U a00, a10, w0;
        a00.v = *(const float4*)(pA0);
        a10.v = *(const float4*)(pA1);
        w0.v  = *(const float4*)(pWD);
        bool q0 = (q == 0);
        SF shi0;
#pragma unroll
        for (int h = 0; h < 2; h++){
            float2 p00 = f2fma(DD0, w0.h[h], f2add(a00.h[h], b0a.h[h]));
            float2 s00 = sig2s(p00);
            shi0.w[h] = q0 ? pk_bf16(s00.x, s00.y) : 0u;
        }
        shi0.w[2] = q0 ? 0x3F80u : 0u;   // e4 = k260 = 1.0 (bf16), e5 = 0
        shi0.w[3] = 0u;
        acc0 = __builtin_amdgcn_mfma_f32_32x32x16_bf16(shi0.v, wh.v, acc0, 0, 0, 0);
        if (!skip1){
            SF shi1;
#pragma unroll
            for (int h = 0; h < 2; h++){
                float2 p10 = f2fma(DD1, w0.h[h], f2add(a10.h[h], b1a.h[h]));
                float2 s10 = sig2s(p10);
                shi1.w[h] = q0 ? pk_bf16(s10.x, s10.y) : 0u;
            }
            shi1.w[2] = q0 ? 0x3F80u : 0u;
            shi1.w[3] = 0u;
            acc1 = __builtin_amdgcn_mfma_f32_32x32x16_bf16(shi1.v, wh.v, acc1, 0, 0, 0);
        }
    }

    // ---- m = silu'(acc) (bias already in acc via k=260 column); paired sig2s;
    //      masked m_i sum (x -ln2); (DOCW) repack to LDS bf16.
    //      skip1 waves: acc1 == 0 -> s1 == 0 -> masked rows get 0 as required.
    u16* mlds = (u16*)myk;               // overwrites A stage (done with it)
    float msum = 0.0f;
#pragma unroll
    for (int r = 0; r < 16; r += 2){
        int row = (r&3) + 8*(r>>2) + 4*q;
        float2 s0 = sig2s(float2{acc0[r], acc0[r+1]});
        float2 s1 = sig2s(float2{acc1[r], acc1[r+1]});
        float m00 = (tile*64 + row     < kl) ? s0.x : 0.0f;
        float m01 = (tile*64 + row + 1 < kl) ? s0.y : 0.0f;
        float m10 = (tile*64 + 32 + row     < kl) ? s1.x : 0.0f;
        float m11 = (tile*64 + 32 + row + 1 < kl) ? s1.y : 0.0f;
        msum += (m00 + m01) + (m10 + m11);
        if (DOCW){
            mlds[row*MSTR + n]      = bf16_rne(m00);
            mlds[(row+1)*MSTR + n]  = bf16_rne(m01);
            mlds[(row+32)*MSTR + n] = bf16_rne(m10);
            mlds[(row+33)*MSTR + n] = bf16_rne(m11);
        }
    }
    msum += __shfl_xor(msum, 32);
    if (!dead && lane < MD) atomicAdd(&mi[u*20 + lane], msum * LN2N);

    if (DOCW){
        lgkm_wait();
        const char* mb = (const char*)mlds;
        float gx = 0.0f, gy = 0.0f, gz = 0.0f;
        float bc2v = bc2[jl];
#pragma unroll
        for (int S = 0; S < 2; S++){
            SF af0, af1;
            af0.i4 = *(const int4*)(mb + (S*32+n)*(MSTR*2) + q*16);
            af1.i4 = *(const int4*)(mb + (S*32+n)*(MSTR*2) + 32 + q*16);
            float cwp[16];
#pragma unroll
            for (int r = 0; r < 16; r++) cwp[r] = 0.0f;
            for (int T = 0; T < 3; T++){
                SF bb0, bb1;
                bb0.i4 = *(const int4*)(Wc1f + jl*3072 + T*1024 +       lane*8);
                bb1.i4 = *(const int4*)(Wc1f + jl*3072 + T*1024 + 512 + lane*8);
                f32x16 p2;
#pragma unroll
                for (int r = 0; r < 16; r++) p2[r] = 0.0f;
                p2 = __builtin_amdgcn_mfma_f32_32x32x16_bf16(af0.v, bb0.v, p2, 0, 0, 0);
                p2 = __builtin_amdgcn_mfma_f32_32x32x16_bf16(af1.v, bb1.v, p2, 0, 0, 0);
                float bc1v = bc1P[jl*96 + T*32 + n];
                float wc2v = Wc2P[jl*96 + T*32 + n];
#pragma unroll
                for (int r = 0; r < 16; r++)
                    cwp[r] = fmaf(silups(p2[r] + bc1v), wc2v, cwp[r]);
            }
#pragma unroll
            for (int r = 0; r < 16; r++){
                int row  = (r&3) + 8*(r>>2) + 4*q + S*32;
                int brow = tile*64 + row;
                F4U cbr; cbr.v = ((const float4*)cin)[off + min(brow, kl-1)];
                float cw = cwp[r] + ((n == 0) ? bc2v : 0.0f);
                cw = (brow < kl) ? cw : 0.0f;
                gx = fmaf(cw, ca.f[0]-cbr.f[0], gx);
                gy = fmaf(cw, ca.f[1]-cbr.f[1], gy);
                gz = fmaf(cw, ca.f[2]-cbr.f[2], gz);
            }
        }
#pragma unroll
        for (int s = 1; s < 64; s <<= 1){
            gx += __shfl_xor(gx, s); gy += __shfl_xor(gy, s); gz += __shfl_xor(gz, s);
        }
        if (!dead && lane == 0){
            atomicAdd(&cout[u*4+0], gx);
            atomicAdd(&cout[u*4+1], gy);
            atomicAdd(&cout[u*4+2], gz);
        }
    }
}

// ============ node MLP + (optionally) AB for next layer + inits ==============
// Final layer (donext==0): fused scatter-max into out via u32 atomicMax
// (valid: hn >= 0 after relu; out zero-initialized in k_pre).
__global__ __launch_bounds__(256) void k_nodeab(
    int jl, int donext, int docopy,
    const float* __restrict__ Wn1, const float* __restrict__ bn1,
    const float* __restrict__ Wn2, const float* __restrict__ bn2,
    const float* __restrict__ We1, const float* __restrict__ be1,
    float* __restrict__ hc, float* __restrict__ mi,
    const float* __restrict__ ccur, float* __restrict__ cnext,
    float* __restrict__ Ap, float* __restrict__ BF,
    const int* __restrict__ sidx, float* __restrict__ outv){
    int t = threadIdx.x; int u = blockIdx.x*4 + (t>>6); if (u >= KT) return;
    int lane = t&63;
    float hval = hc[u*DIMF+lane];
    float mval = (lane < MD) ? mi[u*20+lane] : 0.0f;
    const float* W1 = Wn1 + jl*(DIMF+MD)*NH1;
    float v0 = bn1[jl*NH1+lane], v1 = bn1[jl*NH1+lane+64];
    for (int d = 0; d < DIMF; d++){
        float x = __shfl(hval, d);
        v0 = fmaf(x, W1[d*NH1+lane],    v0);
        v1 = fmaf(x, W1[d*NH1+lane+64], v1);
    }
    for (int d = 0; d < MD; d++){
        float x = __shfl(mval, d);
        v0 = fmaf(x, W1[(DIMF+d)*NH1+lane],    v0);
        v1 = fmaf(x, W1[(DIMF+d)*NH1+lane+64], v1);
    }
    float s0 = silups(v0 * KNEG) * LN2N, s1 = silups(v1 * KNEG) * LN2N;
    const float* W2 = Wn2 + jl*NH1*DIMF;
    float h = bn2[jl*DIMF+lane];
    for (int i = 0; i < 64; i++) h = fmaf(__shfl(s0, i), W2[i*DIMF+lane], h);
    for (int i = 0; i < 64; i++) h = fmaf(__shfl(s1, i), W2[(64+i)*DIMF+lane], h);
    float hn = fmaxf(0.0f, fmaf(2.0f, hval, h));
    hc[u*DIMF+lane] = hn;
    if (donext){
        if (lane < 20) mi[u*20+lane] = 0.0f;
        if (docopy && lane < 4) cnext[u*4+lane] = ccur[u*4+lane];
        ab_comp(jl+1, We1, be1, hn, u, lane, Ap, BF);
    } else {
        int l2 = (u<K0)?0:(u<O2)?1:2;
        int a2 = u - ((l2==0)?0:(l2==1)?O1:O2);
        int org = sidx[l2*NN+a2];
        atomicMax((u32*)&outv[org*DIMF+lane], __float_as_uint(hn));
    }
}

extern "C" void kernel_launch(void* const* d_in, const int* in_sizes, int n_in,
                              void* d_out, int out_size, void* d_ws, size_t ws_size,
                              hipStream_t stream) {
    (void)in_sizes; (void)n_in; (void)out_size; (void)ws_size;
    const float* feat = (const float*)d_in[0];
    const float* coor = (const float*)d_in[1];
    const float* edge = (const float*)d_in[2];
    const float* We1  = (const float*)d_in[3];
    const float* be1  = (const float*)d_in[4];
    const float* We2  = (const float*)d_in[5];
    const float* be2  = (const float*)d_in[6];
    const float* Wc1  = (const float*)d_in[7];
    const float* bc1  = (const float*)d_in[8];
    const float* Wc2  = (const float*)d_in[9];
    const float* bc2  = (const float*)d_in[10];
    const float* Wn1  = (const float*)d_in[11];
    const float* bn1  = (const float*)d_in[12];
    const float* Wn2  = (const float*)d_in[13];
    const float* bn2  = (const float*)d_in[14];
    const float* wp   = (const float*)d_in[15];
    const float* bp   = (const float*)d_in[16];
    float* out = (float*)d_out;

    char* wsb = (char*)d_ws;
    u64*   ugw    = (u64*)  (wsb + 0);         // 32768
    u64*   ug2w   = (u64*)  (wsb + 32768);     // 32768
    float* scores = (float*)(wsb + 65536);     // 6144
    float* svals  = (float*)(wsb + 71680);     // 6144
    int*   sidx   = (int*)  (wsb + 77824);     // 6144
    int*   rev    = (int*)  (wsb + 83968);     // 6144
    float* c0     = (float*)(wsb + 90112);     // 18432
    float* c1     = (float*)(wsb + 108544);    // 18432
    float* mi     = (float*)(wsb + 126976);    // 90112
    float* hc     = (float*)(wsb + 217088);    // 288256
    float* Ap     = (float*)(wsb + 505344);    // 1224192
    float* BF     = (float*)(wsb + 1729536);   // 1253376 (34*1152*8*4)
    u16*   W2f    = (u16*)  (wsb + 2982912);   // 52224 (3*17*512*2, hi-only)
    u16*   Wc1f   = (u16*)  (wsb + 3087360);   // 18432
    float* wdP    = (float*)(wsb + 3105792);   // 3328
    float* weP    = (float*)(wsb + 3109120);   // 3328
    float* be2P   = (float*)(wsb + 3112448);   // 384
    float* bc1P   = (float*)(wsb + 3112832);   // 1152
    float* Wc2P   = (float*)(wsb + 3113984);   // 1152  (end ~3.12 MB)

    k_pre<<<425, 256, 0, stream>>>(edge, feat, wp, bp, We2, Wc1, We1, be2, bc1, Wc2,
                                   ugw, scores, W2f, Wc1f,
                                   wdP, weP, be2P, bc1P, Wc2P, ug2w, out);
    k_sortug2<<<67, 512, 0, stream>>>(scores, ugw, svals, sidx, rev, ug2w);
    k_gab<<<282, 256, 0, stream>>>(feat, coor, svals, sidx, We1, be1,
                                   hc, c0, c1, mi, Ap, BF);
    // layer 0: cin=c0, cout=c1
    k_pair<1><<<PBLK, 256, 0, stream>>>(0, Ap, BF, W2f, Wc1f,
                                        wdP, weP, be2P, bc1P, Wc2P, bc2,
                                        c0, c1, mi, sidx, ug2w);
    k_nodeab<<<282, 256, 0, stream>>>(0, 1, 1, Wn1, bn1, Wn2, bn2, We1, be1,
                                      hc, mi, c1, c0, Ap, BF, sidx, out);
    // layer 1: cin=c1, cout=c0 (pre-initialized to c1 by k_nodeab)
    k_pair<1><<<PBLK, 256, 0, stream>>>(1, Ap, BF, W2f, Wc1f,
                                        wdP, weP, be2P, bc1P, Wc2P, bc2,
                                        c1, c0, mi, sidx, ug2w);
    k_nodeab<<<282, 256, 0, stream>>>(1, 1, 0, Wn1, bn1, Wn2, bn2, We1, be1,
                                      hc, mi, c0, c1, Ap, BF, sidx, out);
    // layer 2: coords output unused -> no coord MLP instantiation
    k_pair<0><<<PBLK, 256, 0, stream>>>(2, Ap, BF, W2f, Wc1f,
                                        wdP, weP, be2P, bc1P, Wc2P, bc2,
                                        c0, c1, mi, sidx, ug2w);
    // final: node MLP + fused scatter-max into out (replaces k_final)
    k_nodeab<<<282, 256, 0, stream>>>(2, 0, 0, Wn1, bn1, Wn2, bn2, We1, be1,
                                      hc, mi, c0, c1, Ap, BF, sidx, out);
}

// Round 10
// 338.606 us; speedup vs baseline: 1.0264x; 1.0252x over previous
//
// R10 = consolidation of best-measured pieces: R6 small kernels (NO unroll-8 —
// R7 showed it spills, +10us) + R7 k_pair (skip1 + sWD staged in LDS, 77.2us
// measured). R9's global-wd read cost +2.8us/dispatch (vmcnt-queue contention
// with B-prefetch) — reverted. LDS diet abandoned: grid is 7.19 blocks/CU so
// the 7-block cap already holds it; occupancy metric insensitive (R9).
#include <hip/hip_runtime.h>
#include <hip/hip_bf16.h>

typedef unsigned long long u64;
typedef unsigned int u32;
typedef unsigned short u16;

#define NN   512
#define DIMF 64
#define E2   260
#define KPAD 272
#define MD   17
#define MH   68
#define NH1  128
#define K0   460
#define K1   358
#define K2   307
#define KT   1125
#define O1   460
#define O2   818
#define PADU 1152
#define AS   272
// 64-sender tiles per receiver, one wave each (2 MFMA acc sets of 32)
#define NT0  8
#define NT1  6
#define NT2  5
#define T0T   (K0*NT0)          // 3680
#define T01T  (T0T + K1*NT1)    // 5828
#define TTOT  (T01T + K2*NT2)   // 7363
#define PBLK  ((TTOT+3)/4)      // 1841
#define MSTR  40                // u16 stride of m-repack rows (80 B: 16B-aligned
                                // rows for ds_read_b128; R6-proven. NOT 38!)
#define WVLDS 5120              // per-wave LDS scratch bytes (A stage 2176 < 5120)

// prescale constants: sigma(z) = rcp(1 + exp2(q)), q = -log2(e)*z; ln2*log2e == 1
#define KNEG  (-1.4426950408889634f)
#define LN2N  (-0.6931471805599453f)

typedef __attribute__((ext_vector_type(8)))  short short8;
typedef __attribute__((ext_vector_type(16))) float f32x16;

union SF  { int4 i4; u16 us[8]; u32 w[4]; short8 v; };
union F4U { float4 v; float2 h[2]; float f[4]; u32 w[4]; };

__device__ __forceinline__ float fast_exp2(float x){
#if __has_builtin(__builtin_amdgcn_exp2f)
    return __builtin_amdgcn_exp2f(x);
#else
    return __expf(x * 0.6931471805599453f);
#endif
}
__device__ __forceinline__ float fast_rcp(float x){
#if __has_builtin(__builtin_amdgcn_rcpf)
    return __builtin_amdgcn_rcpf(x);
#else
    return __fdividef(1.0f, x);
#endif
}
// prescaled silu: input q = -log2e * z, returns -log2e * silu(z)
__device__ __forceinline__ float silups(float q){
    return q * fast_rcp(1.0f + fast_exp2(q));
}
__device__ __forceinline__ float sigf(float x){
    return fast_rcp(1.0f + fast_exp2(x * KNEG));
}
__device__ __forceinline__ u16 bf16_rne(float f){
    u32 u = __float_as_uint(f);
    u += 0x7FFFu + ((u >> 16) & 1u);
    return (u16)(u >> 16);
}
__device__ __forceinline__ float bf16f(u16 h){
    return __uint_as_float(((u32)h) << 16);
}
// packed RNE bf16x2 (v_cvt_pk_bf16_f32 on gfx950)
__device__ __forceinline__ u32 pk_bf16(float x, float y){
    float2 f2; f2.x = x; f2.y = y;
    __hip_bfloat162 h = __float22bfloat162_rn(f2);
    union { __hip_bfloat162 b; u32 u; } cv; cv.b = h;
    return cv.u;
}
__device__ __forceinline__ void lgkm_wait(){
#if __has_builtin(__builtin_amdgcn_s_waitcnt)
    __builtin_amdgcn_s_waitcnt(0xC07F);   // lgkmcnt(0)
#endif
}
// packed float2 helpers (SLP-friendly -> v_pk_fma_f32 / v_pk_add_f32 / v_pk_mul_f32)
__device__ __forceinline__ float2 f2add(float2 a, float2 b){ return float2{a.x+b.x, a.y+b.y}; }
__device__ __forceinline__ float2 f2mul(float2 a, float2 b){ return float2{a.x*b.x, a.y*b.y}; }
__device__ __forceinline__ float2 f2fma(float2 a, float2 b, float2 c){
    return float2{fmaf(a.x,b.x,c.x), fmaf(a.y,b.y,c.y)};
}
// prescaled paired silu, rcp form. R3 post-mortem: this (4 trans + 2 pk) BEATS
// the deg-4 poly form (2 trans + 8 pk) on gfx950 — trans ops issue cheaply;
// total VALU slots dominate. Do NOT re-introduce sig2p.
__device__ __forceinline__ float2 sig2s(float2 q){
    float ex = fast_exp2(q.x), ey = fast_exp2(q.y);
    float2 den = f2add(float2{1.0f, 1.0f}, float2{ex, ey});
    float rx = fast_rcp(den.x), ry = fast_rcp(den.y);
    return f2mul(q, float2{rx, ry});
}

// ============ fused prep: ug bitmasks + pooling scores + weight fragments ===
__global__ __launch_bounds__(256) void k_pre(
    const float* __restrict__ edge, const float* __restrict__ feat,
    const float* __restrict__ wp, const float* __restrict__ bp,
    const float* __restrict__ We2, const float* __restrict__ Wc1,
    const float* __restrict__ We1, const float* __restrict__ be2,
    const float* __restrict__ bc1, const float* __restrict__ Wc2,
    u64* __restrict__ ugw, float* __restrict__ scores,
    u16* __restrict__ W2f, u16* __restrict__ Wc1f,
    float* __restrict__ wdP, float* __restrict__ weP, float* __restrict__ be2P,
    float* __restrict__ bc1P, float* __restrict__ Wc2P, u64* __restrict__ ug2w,
    float* __restrict__ outz){
    int blk = blockIdx.x, t = threadIdx.x;
    if (blk < 128){                      // ug row bitmasks, 4 rows/block
        int i = blk*4 + (t>>6); int lane = t&63;
        const float* row = edge + (size_t)i*NN;
        for (int w = 0; w < 8; w++){
            u64 m = __ballot(row[w*64+lane] != 0.0f);
            if (lane == 0) ugw[i*8+w] = m;
        }
        return;
    }
    if (blk < 134){                      // pooling scores (float4 dot)
        int gid = (blk-128)*256 + t; if (gid >= 3*NN) return;
        int l = gid>>9, n = gid&511;
        const float4* fr = (const float4*)(feat + n*DIMF);
        const float4* wr = (const float4*)(wp + l*DIMF);
        float s = bp[l];
        for (int d = 0; d < 16; d++){
            float4 f = fr[d], w = wr[d];
            s = fmaf(f.x, w.x, s); s = fmaf(f.y, w.y, s);
            s = fmaf(f.z, w.z, s); s = fmaf(f.w, w.w, s);
        }
        scores[gid] = sigf(s);
        return;
    }
    int idx = (blk-134)*256 + t;
    if (idx < 26112){                    // We2 frags hi-only: [jl][c17][lane64][8]
        // k==260 pad slot carries the prescaled be2 bias column (s'[260]==1).
        int e = idx&7, lane = (idx>>3)&63, c = (idx>>9)%17, jl = idx/8704;
        int q = lane>>5, nn = lane&31;
        int k = c*16 + q*8 + e;
        float v = (k < E2 && nn < MD) ? We2[jl*E2*MD + k*MD + nn]
                : (k == 260 && nn < MD) ? be2[jl*MD+nn]*KNEG : 0.0f;
        W2f[idx] = bf16_rne(v);
        return;
    }
    idx -= 26112;
    if (idx < 9216){                     // Wc1 frags: [jl][T3][c2][lane][8]
        int e = idx & 7, lane = (idx>>3)&63, c2 = (idx>>9)&1, T = (idx>>10)%3, jl = idx/3072;
        int q = lane>>5, nn = lane&31;
        int o = c2*16 + q*8 + e, h = T*32 + nn;
        float v = (o < MD && h < MH) ? Wc1[jl*MD*MH + o*MH + h] : 0.0f;
        Wc1f[idx] = bf16_rne(v);
        return;
    }
    idx -= 9216;
    if (idx < 816){ int jl = idx/KPAD, k = idx%KPAD;
        wdP[idx] = (k < E2) ? We1[jl*130*E2 + 128*E2 + k]*KNEG : 0.0f; return; }
    idx -= 816;
    if (idx < 816){ int jl = idx/KPAD, k = idx%KPAD;
        weP[idx] = (k < E2) ? We1[jl*130*E2 + 129*E2 + k]*KNEG : 0.0f; return; }
    idx -= 816;
    if (idx < 96){ int jl = idx/32, o = idx%32;
        be2P[idx] = (o < MD) ? be2[jl*MD+o]*KNEG : 0.0f; return; }
    idx -= 96;
    if (idx < 288){ int jl = idx/96, h = idx%96;
        bc1P[idx] = (h < MH) ? bc1[jl*MH+h]*KNEG : 0.0f; return; }
    idx -= 288;
    if (idx < 288){ int jl = idx/96, h = idx%96;
        Wc2P[idx] = (h < MH) ? Wc2[jl*MH+h]*LN2N : 0.0f; return; }
    idx -= 288;
    if (idx < 4096){ ug2w[idx] = 0ULL; return; }   // zero for k_sortug2's atomicOr
    idx -= 4096;
    if (idx < NN*DIMF){ outz[idx] = 0.0f; return; } // zero out for fused atomicMax scatter
}

// ============ fused: bitonic sort (3 blocks) + ug2 bitset matmul (64 blocks) =
// sort: shfl-register bitonic for jj<=32 (39 of 45 rounds barrier-free)
__global__ __launch_bounds__(512) void k_sortug2(
    const float* __restrict__ scores, const u64* __restrict__ ugw,
    float* __restrict__ svals, int* __restrict__ sidx, int* __restrict__ rev,
    u64* __restrict__ ug2w){
    int blk = blockIdx.x, t = threadIdx.x;
    if (blk < 3){
        int l = blk;
        __shared__ float sk[NN];
        __shared__ int   si[NN];
        float key = scores[l*NN+t]; int idx = t;
        rev[l*NN+t] = -1;
        for (int k = 2; k <= NN; k <<= 1){
            for (int jj = k>>1; jj > 0; jj >>= 1){
                float kb; int ib;
                if (jj >= 64){
                    sk[t] = key; si[t] = idx;
                    __syncthreads();
                    kb = sk[t^jj]; ib = si[t^jj];
                    __syncthreads();
                } else {
                    kb = __shfl_xor(key, jj);
                    ib = __shfl_xor(idx, jj);
                }
                bool aFirst = (key > kb) || (key == kb && idx < ib);
                bool down   = ((t & k) == 0);
                bool lower  = ((t & jj) == 0);
                bool keep   = (aFirst == (lower == down));
                key = keep ? key : kb;
                idx = keep ? idx : ib;
            }
        }
        svals[l*NN+t] = key; sidx[l*NN+t] = idx;
        int kcnt = (l==0)?K0:(l==1)?K1:K2;
        if (t < kcnt) rev[l*NN + idx] = t;
    } else {
        // (i, w, kc): row i, out-word w, row-mask word kc. Iterate SET BITS only.
        int gid = (blk-3)*512 + t;       // 32768 total
        int i  = gid >> 6;
        int w  = (gid >> 3) & 7;
        int kc = gid & 7;
        u64 rm = ugw[i*8 + kc];
        u64 acc = 0;
        int base = kc*64;
        while (rm){
            int k2 = __builtin_ctzll(rm);
            rm &= rm - 1;
            acc |= ugw[(base + k2)*8 + w];
        }
        if (acc) atomicOr(&ug2w[i*8 + w], acc);
    }
}

// ============ A/B precompute ================================================
// A row-major per node (zero-padded k 260..271); B in BF[k>>3][u][k&7] groups.
// Outputs prescaled by -log2e so k_pair's silu skips the scale multiply.
// NOTE (R7): do NOT unroll the d-loop — 8x unroll spilled (16 float4 load
// dests in flight) and cost +10us across k_gab/k_nodeab.
__device__ __forceinline__ void ab_comp(int jl, const float* __restrict__ We1,
                                        const float* __restrict__ be1, float hval,
                                        int u, int lane,
                                        float* __restrict__ Ap, float* __restrict__ BF){
    const float* W = We1 + jl*130*E2;
    int r  = 4*lane;
    int rt = 256 + lane;
    int rtc = (lane < 4) ? rt : 256;
    F4U av; av.v = *(const float4*)(be1 + jl*E2 + r);
    F4U bv; bv.f[0]=bv.f[1]=bv.f[2]=bv.f[3]=0.0f;
    float avx = be1[jl*E2 + rtc];
    float bvx = 0.0f;
    for (int d = 0; d < DIMF; d++){
        float hv = __shfl(hval, d);
        F4U w1; w1.v = *(const float4*)(W + d*E2 + r);
        F4U w2; w2.v = *(const float4*)(W + (DIMF+d)*E2 + r);
#pragma unroll
        for (int i = 0; i < 4; i++){
            av.f[i] = fmaf(hv, w1.f[i], av.f[i]);
            bv.f[i] = fmaf(hv, w2.f[i], bv.f[i]);
        }
        avx = fmaf(hv, W[d*E2 + rtc], avx);
        bvx = fmaf(hv, W[(DIMF+d)*E2 + rtc], bvx);
    }
#pragma unroll
    for (int i = 0; i < 4; i++){ av.f[i] *= KNEG; bv.f[i] *= KNEG; }
    avx *= KNEG; bvx *= KNEG;
    *(float4*)(Ap + u*AS + r) = av.v;
    *(float4*)(BF + ((size_t)(lane>>1)*PADU + u)*8 + (lane&1)*4) = bv.v;
    if (lane < 16){                     // k = 256..271; zero-pad beyond 259
        int k = 256 + lane;
        float aval = (lane < 4) ? avx : 0.0f;
        float bval = (lane < 4) ? bvx : 0.0f;
        Ap[u*AS + k] = aval;
        BF[((size_t)(k>>3)*PADU + u)*8 + (k&7)] = bval;
    }
}

// ============ gather + AB(layer0) + init mi/c0/c1 ===========================
__global__ __launch_bounds__(256) void k_gab(
    const float* __restrict__ feat, const float* __restrict__ coor,
    const float* __restrict__ svals, const int* __restrict__ sidx,
    const float* __restrict__ We1, const float* __restrict__ be1,
    float* __restrict__ hc, float* __restrict__ c0, float* __restrict__ c1,
    float* __restrict__ mi, float* __restrict__ Ap, float* __restrict__ BF){
    int t = threadIdx.x; int u = blockIdx.x*4 + (t>>6); if (u >= KT) return;
    int lane = t&63;
    int l = (u<K0)?0:(u<O2)?1:2;
    int a = u - ((l==0)?0:(l==1)?O1:O2);
    int org = sidx[l*NN+a];
    float val = svals[l*NN+a];
    float hval = feat[org*DIMF+lane]*val;
    hc[u*DIMF+lane] = hval;
    if (lane < 3){ float c = coor[org*3+lane]; c0[u*4+lane]=c; c1[u*4+lane]=c; }
    if (lane == 3){ c0[u*4+3]=0.0f; c1[u*4+3]=0.0f; }
    if (lane < 20) mi[u*20+lane] = 0.0f;
    ab_comp(0, We1, be1, hval, u, lane, Ap, BF);
}

// ============ per-pair edge MLP via MFMA =====================================
// wave = (receiver u, 64-sender tile): two 32-pair MFMA acc sets.
// PRESCALE pipeline: A/B/wd carry -log2e -> p = q = -log2e*z directly;
// s' = -log2e*silu(z) vs unscaled W2f -> acc = -log2e*(acc_true + be2) via the
// k=260 bias column; Wc2P carries -ln2, msum scaled by -ln2.
// EF-SELECT (R4): stage A and A+E in LDS, lane picks base once.
// PEELED c=16 (R6): last K-iter has 4 real elems (q=0/a0 group) + bias slot.
// SKIP1 (R7): tiles whose acc1 sender block is fully >= kl skip shi1/acc1.
// sWD stays in LDS (R9 showed global-wd costs +2.8us: vmcnt contention).
template<int DOCW>
__global__ __launch_bounds__(256, 4) void k_pair(
    int jl,
    const float* __restrict__ Ap, const float* __restrict__ BF,
    const u16* __restrict__ W2f, const u16* __restrict__ Wc1f,
    const float* __restrict__ wdP, const float* __restrict__ weP,
    const float* __restrict__ be2P, const float* __restrict__ bc1P,
    const float* __restrict__ Wc2P, const float* __restrict__ bc2,
    const float* __restrict__ cin, float* __restrict__ cout,
    float* __restrict__ mi, const int* __restrict__ sidx,
    const u64* __restrict__ ug2w){
    __shared__ __align__(16) char sWK[4*WVLDS];
    __shared__ __align__(16) char sWD[1088];
    int t = threadIdx.x;
    if (t < 68) ((float4*)sWD)[t] = *(const float4*)(wdP + jl*KPAD + 4*t);
    int wid0 = blockIdx.x*4 + (t>>6);
    int lane = t&63, n = lane&31, q = lane>>5;
    bool dead = (wid0 >= TTOT);
    int wid = dead ? (TTOT-1) : wid0;
    int l, kl, off, a, tile;
    if (wid < T0T)       { l=0; kl=K0; off=0;  a = wid>>3; tile = wid&7; }
    else if (wid < T01T) { int w = wid-T0T;  l=1; kl=K1; off=O1; a = w/NT1; tile = w - a*NT1; }
    else                 { int w = wid-T01T; l=2; kl=K2; off=O2; a = w/NT2; tile = w - a*NT2; }
    int u = off + a;
    bool skip1 = (tile*64 + 32 >= kl);   // acc1 sender block fully beyond kl
    int b0 = tile*64 + n, b1 = b0 + 32;
    int b0c = min(b0, kl-1), b1c = min(b1, kl-1);
    int ub0 = off + b0c, ub1 = off + b1c;
    int ia  = sidx[l*NN+a];
    int ib0 = sidx[l*NN+b0c], ib1 = sidx[l*NN+b1c];
    int eb0 = (int)((ug2w[ia*8 + (ib0>>6)] >> (ib0&63)) & 1ULL);
    int eb1 = (int)((ug2w[ia*8 + (ib1>>6)] >> (ib1&63)) & 1ULL);
    int sel0 = (b0 < kl) ? eb0 : 0;
    int sel1 = (b1 < kl) ? eb1 : 0;
    F4U ca;  ca.v  = ((const float4*)cin)[u];
    F4U cb0; cb0.v = ((const float4*)cin)[ub0];
    F4U cb1; cb1.v = ((const float4*)cin)[ub1];
    float tx0 = ca.f[0]-cb0.f[0], ty0 = ca.f[1]-cb0.f[1], tz0 = ca.f[2]-cb0.f[2];
    float tx1 = ca.f[0]-cb1.f[0], ty1 = ca.f[1]-cb1.f[1], tz1 = ca.f[2]-cb1.f[2];
    float dd0 = tx0*tx0 + ty0*ty0 + tz0*tz0;
    float dd1 = tx1*tx1 + ty1*ty1 + tz1*tz1;

    char* myk = sWK + (t>>6)*WVLDS;
    {   // stage A (base, [0,1088)) and A+E (edge-selected, [1088,2176))
        const float* Au = Ap + u*AS;
        const float* Ew = weP + jl*KPAD;
        F4U av; av.v = *(const float4*)(Au + 4*lane);
        F4U ev; ev.v = *(const float4*)(Ew + 4*lane);
        ((float4*)myk)[lane] = av.v;
        F4U sv;
#pragma unroll
        for (int i = 0; i < 4; i++) sv.f[i] = av.f[i] + ev.f[i];
        ((float4*)(myk + 1088))[lane] = sv.v;
        if (lane < 4){
            F4U at; at.v = *(const float4*)(Au + 256 + 4*lane);
            F4U et; et.v = *(const float4*)(Ew + 256 + 4*lane);
            ((float4*)myk)[64+lane] = at.v;
            F4U st;
#pragma unroll
            for (int i = 0; i < 4; i++) st.f[i] = at.f[i] + et.f[i];
            ((float4*)(myk + 1088))[64+lane] = st.v;
        }
    }
    __syncthreads();

    const float* pB0 = BF + ((size_t)q*PADU + ub0)*8;
    const float* pB1 = BF + ((size_t)q*PADU + ub1)*8;
    const u16*   pW  = W2f + jl*8704 + lane*8;
    const char*  pA0 = myk + sel0*1088 + q*32;
    const char*  pA1 = myk + sel1*1088 + q*32;
    const char*  pWD = sWD + q*32;

    f32x16 acc0, acc1;
#pragma unroll
    for (int r = 0; r < 16; r++){ acc0[r] = 0.0f; acc1[r] = 0.0f; }

    // prologue loads for c=0 (rotating pipeline, R9 structure)
    F4U nb0a, nb0b, nb1a, nb1b; SF nwh;
    nb0a.v = *(const float4*)(pB0);     nb0b.v = *(const float4*)(pB0 + 4);
    nb1a.v = *(const float4*)(pB1);     nb1b.v = *(const float4*)(pB1 + 4);
    nwh.i4 = *(const int4*)(pW);

    float2 DD0{dd0,dd0}, DD1{dd1,dd1};

    for (int c = 0; c < 16; c++){
        F4U b0a = nb0a, b0b = nb0b, b1a = nb1a, b1b = nb1b;
        SF  wh  = nwh;
        pB0 += 2*PADU*8; pB1 += 2*PADU*8; pW += 512;
        // unconditional prefetch for c+1 (c=15 prefetches the peeled iter's data)
        nb0a.v = *(const float4*)(pB0);     nb0b.v = *(const float4*)(pB0 + 4);
        nb1a.v = *(const float4*)(pB1);     nb1b.v = *(const float4*)(pB1 + 4);
        nwh.i4 = *(const int4*)(pW);
        F4U a00, a01, a10, a11, w0, w1;
        a00.v = *(const float4*)(pA0);     a01.v = *(const float4*)(pA0 + 16);
        a10.v = *(const float4*)(pA1);     a11.v = *(const float4*)(pA1 + 16);
        w0.v  = *(const float4*)(pWD);     w1.v  = *(const float4*)(pWD + 16);
        pA0 += 64; pA1 += 64; pWD += 64;

        SF shi0;
#pragma unroll
        for (int h = 0; h < 2; h++){
            float2 p00 = f2fma(DD0, w0.h[h], f2add(a00.h[h], b0a.h[h]));
            float2 p01 = f2fma(DD0, w1.h[h], f2add(a01.h[h], b0b.h[h]));
            float2 s00 = sig2s(p00), s01 = sig2s(p01);
            shi0.w[h]   = pk_bf16(s00.x, s00.y);
            shi0.w[2+h] = pk_bf16(s01.x, s01.y);
        }
        acc0 = __builtin_amdgcn_mfma_f32_32x32x16_bf16(shi0.v, wh.v, acc0, 0, 0, 0);
        if (!skip1){
            SF shi1;
#pragma unroll
            for (int h = 0; h < 2; h++){
                float2 p10 = f2fma(DD1, w0.h[h], f2add(a10.h[h], b1a.h[h]));
                float2 p11 = f2fma(DD1, w1.h[h], f2add(a11.h[h], b1b.h[h]));
                float2 s10 = sig2s(p10), s11 = sig2s(p11);
                shi1.w[h]   = pk_bf16(s10.x, s10.y);
                shi1.w[2+h] = pk_bf16(s11.x, s11.y);
            }
            acc1 = __builtin_amdgcn_mfma_f32_32x32x16_bf16(shi1.v, wh.v, acc1, 0, 0, 0);
        }
    }

    {   // peeled c=16: real hidden units only k=256..259 (q=0, a0 group);
        // k=260 is the bias column (s'=1.0); all else pad-zero.
        F4U b0a = nb0a, b1a = nb1a;
        SF  wh  = nwh;
        F4U a00, a10, w0;
        a00.v = *(const float4*)(pA0);
        a10.v = *(const float4*)(pA1);
        w0.v  = *(const float4*)(pWD);
        bool q0 = (q == 0);
        SF shi0;
#pragma unroll
        for (int h = 0; h < 2; h++){
            float2 p00 = f2fma(DD0, w0.h[h], f2add(a00.h[h], b0a.h[h]));
            float2 s00 = sig2s(p00);
            shi0.w[h] = q0 ? pk_bf16(s00.x, s00.y) : 0u;
        }
        shi0.w[2] = q0 ? 0x3F80u : 0u;   // e4 = k260 = 1.0 (bf16), e5 = 0
        shi0.w[3] = 0u;
        acc0 = __builtin_amdgcn_mfma_f32_32x32x16_bf16(shi0.v, wh.v, acc0, 0, 0, 0);
        if (!skip1){
            SF shi1;
#pragma unroll
            for (int h = 0; h < 2; h++){
                float2 p10 = f2fma(DD1, w0.h[h], f2add(a10.h[h], b1a.h[h]));
                float2 s10 = sig2s(p10);
                shi1.w[h] = q0 ? pk_bf16(s10.x, s10.y) : 0u;
            }
            shi1.w[2] = q0 ? 0x3F80u : 0u;
            shi1.w[3] = 0u;
            acc1 = __builtin_amdgcn_mfma_f32_32x32x16_bf16(shi1.v, wh.v, acc1, 0, 0, 0);
        }
    }

    // ---- m = silu'(acc) (bias already in acc via k=260 column); paired sig2s;
    //      masked m_i sum (x -ln2); (DOCW) repack to LDS bf16.
    //      skip1 waves: acc1 == 0 -> s1 == 0 -> masked rows get 0 as required.
    u16* mlds = (u16*)myk;               // overwrites A stage (done with it)
    float msum = 0.0f;
#pragma unroll
    for (int r = 0; r < 16; r += 2){
        int row = (r&3) + 8*(r>>2) + 4*q;
        float2 s0 = sig2s(float2{acc0[r], acc0[r+1]});
        float2 s1 = sig2s(float2{acc1[r], acc1[r+1]});
        float m00 = (tile*64 + row     < kl) ? s0.x : 0.0f;
        float m01 = (tile*64 + row + 1 < kl) ? s0.y : 0.0f;
        float m10 = (tile*64 + 32 + row     < kl) ? s1.x : 0.0f;
        float m11 = (tile*64 + 32 + row + 1 < kl) ? s1.y : 0.0f;
        msum += (m00 + m01) + (m10 + m11);
        if (DOCW){
            mlds[row*MSTR + n]      = bf16_rne(m00);
            mlds[(row+1)*MSTR + n]  = bf16_rne(m01);
            mlds[(row+32)*MSTR + n] = bf16_rne(m10);
            mlds[(row+33)*MSTR + n] = bf16_rne(m11);
        }
    }
    msum += __shfl_xor(msum, 32);
    if (!dead && lane < MD) atomicAdd(&mi[u*20 + lane], msum * LN2N);

    if (DOCW){
        lgkm_wait();
        const char* mb = (const char*)mlds;
        float gx = 0.0f, gy = 0.0f, gz = 0.0f;
        float bc2v = bc2[jl];
#pragma unroll
        for (int S = 0; S < 2; S++){
            SF af0, af1;
            af0.i4 = *(const int4*)(mb + (S*32+n)*(MSTR*2) + q*16);
            af1.i4 = *(const int4*)(mb + (S*32+n)*(MSTR*2) + 32 + q*16);
            float cwp[16];
#pragma unroll
            for (int r = 0; r < 16; r++) cwp[r] = 0.0f;
            for (int T = 0; T < 3; T++){
                SF bb0, bb1;
                bb0.i4 = *(const int4*)(Wc1f + jl*3072 + T*1024 +       lane*8);
                bb1.i4 = *(const int4*)(Wc1f + jl*3072 + T*1024 + 512 + lane*8);
                f32x16 p2;
#pragma unroll
                for (int r = 0; r < 16; r++) p2[r] = 0.0f;
                p2 = __builtin_amdgcn_mfma_f32_32x32x16_bf16(af0.v, bb0.v, p2, 0, 0, 0);
                p2 = __builtin_amdgcn_mfma_f32_32x32x16_bf16(af1.v, bb1.v, p2, 0, 0, 0);
                float bc1v = bc1P[jl*96 + T*32 + n];
                float wc2v = Wc2P[jl*96 + T*32 + n];
#pragma unroll
                for (int r = 0; r < 16; r++)
                    cwp[r] = fmaf(silups(p2[r] + bc1v), wc2v, cwp[r]);
            }
#pragma unroll
            for (int r = 0; r < 16; r++){
                int row  = (r&3) + 8*(r>>2) + 4*q + S*32;
                int brow = tile*64 + row;
                F4U cbr; cbr.v = ((const float4*)cin)[off + min(brow, kl-1)];
                float cw = cwp[r] + ((n == 0) ? bc2v : 0.0f);
                cw = (brow < kl) ? cw : 0.0f;
                gx = fmaf(cw, ca.f[0]-cbr.f[0], gx);
                gy = fmaf(cw, ca.f[1]-cbr.f[1], gy);
                gz = fmaf(cw, ca.f[2]-cbr.f[2], gz);
            }
        }
#pragma unroll
        for (int s = 1; s < 64; s <<= 1){
            gx += __shfl_xor(gx, s); gy += __shfl_xor(gy, s); gz += __shfl_xor(gz, s);
        }
        if (!dead && lane == 0){
            atomicAdd(&cout[u*4+0], gx);
            atomicAdd(&cout[u*4+1], gy);
            atomicAdd(&cout[u*4+2], gz);
        }
    }
}

// ============ node MLP + (optionally) AB for next layer + inits ==============
// Final layer (donext==0): fused scatter-max into out via u32 atomicMax
// (valid: hn >= 0 after relu; out zero-initialized in k_pre).
__global__ __launch_bounds__(256) void k_nodeab(
    int jl, int donext, int docopy,
    const float* __restrict__ Wn1, const float* __restrict__ bn1,
    const float* __restrict__ Wn2, const float* __restrict__ bn2,
    const float* __restrict__ We1, const float* __restrict__ be1,
    float* __restrict__ hc, float* __restrict__ mi,
    const float* __restrict__ ccur, float* __restrict__ cnext,
    float* __restrict__ Ap, float* __restrict__ BF,
    const int* __restrict__ sidx, float* __restrict__ outv){
    int t = threadIdx.x; int u = blockIdx.x*4 + (t>>6); if (u >= KT) return;
    int lane = t&63;
    float hval = hc[u*DIMF+lane];
    float mval = (lane < MD) ? mi[u*20+lane] : 0.0f;
    const float* W1 = Wn1 + jl*(DIMF+MD)*NH1;
    float v0 = bn1[jl*NH1+lane], v1 = bn1[jl*NH1+lane+64];
    for (int d = 0; d < DIMF; d++){
        float x = __shfl(hval, d);
        v0 = fmaf(x, W1[d*NH1+lane],    v0);
        v1 = fmaf(x, W1[d*NH1+lane+64], v1);
    }
    for (int d = 0; d < MD; d++){
        float x = __shfl(mval, d);
        v0 = fmaf(x, W1[(DIMF+d)*NH1+lane],    v0);
        v1 = fmaf(x, W1[(DIMF+d)*NH1+lane+64], v1);
    }
    float s0 = silups(v0 * KNEG) * LN2N, s1 = silups(v1 * KNEG) * LN2N;
    const float* W2 = Wn2 + jl*NH1*DIMF;
    float h = bn2[jl*DIMF+lane];
    for (int i = 0; i < 64; i++) h = fmaf(__shfl(s0, i), W2[i*DIMF+lane], h);
    for (int i = 0; i < 64; i++) h = fmaf(__shfl(s1, i), W2[(64+i)*DIMF+lane], h);
    float hn = fmaxf(0.0f, fmaf(2.0f, hval, h));
    hc[u*DIMF+lane] = hn;
    if (donext){
        if (lane < 20) mi[u*20+lane] = 0.0f;
        if (docopy && lane < 4) cnext[u*4+lane] = ccur[u*4+lane];
        ab_comp(jl+1, We1, be1, hn, u, lane, Ap, BF);
    } else {
        int l2 = (u<K0)?0:(u<O2)?1:2;
        int a2 = u - ((l2==0)?0:(l2==1)?O1:O2);
        int org = sidx[l2*NN+a2];
        atomicMax((u32*)&outv[org*DIMF+lane], __float_as_uint(hn));
    }
}

extern "C" void kernel_launch(void* const* d_in, const int* in_sizes, int n_in,
                              void* d_out, int out_size, void* d_ws, size_t ws_size,
                              hipStream_t stream) {
    (void)in_sizes; (void)n_in; (void)out_size; (void)ws_size;
    const float* feat = (const float*)d_in[0];
    const float* coor = (const float*)d_in[1];
    const float* edge = (const float*)d_in[2];
    const float* We1  = (const float*)d_in[3];
    const float* be1  = (const float*)d_in[4];
    const float* We2  = (const float*)d_in[5];
    const float* be2  = (const float*)d_in[6];
    const float* Wc1  = (const float*)d_in[7];
    const float* bc1  = (const float*)d_in[8];
    const float* Wc2  = (const float*)d_in[9];
    const float* bc2  = (const float*)d_in[10];
    const float* Wn1  = (const float*)d_in[11];
    const float* bn1  = (const float*)d_in[12];
    const float* Wn2  = (const float*)d_in[13];
    const float* bn2  = (const float*)d_in[14];
    const float* wp   = (const float*)d_in[15];
    const float* bp   = (const float*)d_in[16];
    float* out = (float*)d_out;

    char* wsb = (char*)d_ws;
    u64*   ugw    = (u64*)  (wsb + 0);         // 32768
    u64*   ug2w   = (u64*)  (wsb + 32768);     // 32768
    float* scores = (float*)(wsb + 65536);     // 6144
    float* svals  = (float*)(wsb + 71680);     // 6144
    int*   sidx   = (int*)  (wsb + 77824);     // 6144
    int*   rev    = (int*)  (wsb + 83968);     // 6144
    float* c0     = (float*)(wsb + 90112);     // 18432
    float* c1     = (float*)(wsb + 108544);    // 18432
    float* mi     = (float*)(wsb + 126976);    // 90112
    float* hc     = (float*)(wsb + 217088);    // 288256
    float* Ap     = (float*)(wsb + 505344);    // 1224192
    float* BF     = (float*)(wsb + 1729536);   // 1253376 (34*1152*8*4)
    u16*   W2f    = (u16*)  (wsb + 2982912);   // 52224 (3*17*512*2, hi-only)
    u16*   Wc1f   = (u16*)  (wsb + 3087360);   // 18432
    float* wdP    = (float*)(wsb + 3105792);   // 3328
    float* weP    = (float*)(wsb + 3109120);   // 3328
    float* be2P   = (float*)(wsb + 3112448);   // 384
    float* bc1P   = (float*)(wsb + 3112832);   // 1152
    float* Wc2P   = (float*)(wsb + 3113984);   // 1152  (end ~3.12 MB)

    k_pre<<<425, 256, 0, stream>>>(edge, feat, wp, bp, We2, Wc1, We1, be2, bc1, Wc2,
                                   ugw, scores, W2f, Wc1f,
                                   wdP, weP, be2P, bc1P, Wc2P, ug2w, out);
    k_sortug2<<<67, 512, 0, stream>>>(scores, ugw, svals, sidx, rev, ug2w);
    k_gab<<<282, 256, 0, stream>>>(feat, coor, svals, sidx, We1, be1,
                                   hc, c0, c1, mi, Ap, BF);
    // layer 0: cin=c0, cout=c1
    k_pair<1><<<PBLK, 256, 0, stream>>>(0, Ap, BF, W2f, Wc1f,
                                        wdP, weP, be2P, bc1P, Wc2P, bc2,
                                        c0, c1, mi, sidx, ug2w);
    k_nodeab<<<282, 256, 0, stream>>>(0, 1, 1, Wn1, bn1, Wn2, bn2, We1, be1,
                                      hc, mi, c1, c0, Ap, BF, sidx, out);
    // layer 1: cin=c1, cout=c0 (pre-initialized to c1 by k_nodeab)
    k_pair<1><<<PBLK, 256, 0, stream>>>(1, Ap, BF, W2f, Wc1f,
                                        wdP, weP, be2P, bc1P, Wc2P, bc2,
                                        c1, c0, mi, sidx, ug2w);
    k_nodeab<<<282, 256, 0, stream>>>(1, 1, 0, Wn1, bn1, Wn2, bn2, We1, be1,
                                      hc, mi, c0, c1, Ap, BF, sidx, out);
    // layer 2: coords output unused -> no coord MLP instantiation
    k_pair<0><<<PBLK, 256, 0, stream>>>(2, Ap, BF, W2f, Wc1f,
                                        wdP, weP, be2P, bc1P, Wc2P, bc2,
                                        c0, c1, mi, sidx, ug2w);
    // final: node MLP + fused scatter-max into out (replaces k_final)
    k_nodeab<<<282, 256, 0, stream>>>(2, 0, 0, Wn1, bn1, Wn2, bn2, We1, be1,
                                      hc, mi, c0, c1, Ap, BF, sidx, out);
}